// Round 5
// baseline (377.424 us; speedup 1.0000x reference)
//
#include <hip/hip_runtime.h>
#include <math.h>
#include <stdint.h>

#define D 128
#define EPS 1e-6f
typedef unsigned short u16;

// ---------------------------------------------------------------------------
// state layout (floats), 16B-aligned base:
//   st[0..127]   : q
//   st[128..255] : q_plus
//   st[256..383] : hop accumulator (device atomicAdd targets)
//   st[384]      : ||q||   st[385] : ||q_plus||   st[386] : sum-of-exp
// Rules: no device fences after bulk writes (r6); no global atomic scatters
// (r8); reducer grids <= 1024 blocks (r10); 1-block serial gathers are
// latency traps (r11); grid.sync >> launch gap (r14).
// r15/r17 (gather model, rounds 2+4): gather time ~= HBM FETCH bytes / 3.4
// TB/s. Round-2 row-major 256B gathers: 72us/233MB. Round-4 slice-outer 64B
// reads: 107us/362MB — 64B requests waste half of each 128B line AND 6.4MB
// eff. footprint misses L2. Lesson: chunk by CONTIGUOUS ADDRESS RANGE at
// >=128B granularity, never by strided sub-row slices.
// r18 (this round): id-range chunking — pass c gathers only ids in
// [cV/4,(c+1)V/4): 3.2MB contiguous, L2-resident, full line use; ids+partials
// live in regs across passes. Target FETCH ~115MB.
// ---------------------------------------------------------------------------

__device__ __forceinline__ float wave_sum(float v) {
#pragma unroll
    for (int off = 32; off > 0; off >>= 1) v += __shfl_xor(v, off, 64);
    return v;
}
__device__ __forceinline__ float halfwave_sum(float v) {
#pragma unroll
    for (int off = 16; off > 0; off >>= 1) v += __shfl_xor(v, off, 32);
    return v;
}

__device__ __forceinline__ float bf2f(u16 h) {
    union { unsigned u; float f; } x;
    x.u = ((unsigned)h) << 16;
    return x.f;
}
__device__ __forceinline__ float bflo(unsigned u) { return bf2f((u16)(u & 0xffff)); }
__device__ __forceinline__ float bfhi(unsigned u) { return bf2f((u16)(u >> 16)); }
__device__ __forceinline__ u16 f2bf(float f) {  // round-to-nearest-even
    union { float f; unsigned u; } x;
    x.f = f;
    unsigned u = x.u;
    return (u16)((u + 0x7fff + ((u >> 16) & 1)) >> 16);
}
__device__ __forceinline__ unsigned pack2(float a, float b) {
    return (unsigned)f2bf(a) | ((unsigned)f2bf(b) << 16);
}

// ===========================================================================
// prep_k: blocks [0,nbA) convert semb fp32 -> bf16 ROW-MAJOR (coalesced both
// sides); last 3 blocks do the small encodes (persona rows + q).
// ===========================================================================
__global__ void prep_k(const float* __restrict__ semb, u16* __restrict__ tbl,
                       int V, const int* __restrict__ pers, int NP,
                       const int* __restrict__ xs, int LQ,
                       float* __restrict__ enc_pers, float* __restrict__ pnorms,
                       float* __restrict__ st, int nbA) {
    const int tid = threadIdx.x;
    const int bid = blockIdx.x;
    if (bid < nbA) {
        const int n = V * 64;  // channel-pairs
        const int stride = nbA * 256;
        for (int i = bid * 256 + tid; i < n; i += stride) {
            const int v = i >> 6;
            const int c2 = i & 63;
            const float2 ab = *(const float2*)(semb + (long)v * D + 2 * c2);
            *(unsigned*)(tbl + (long)v * D + 2 * c2) = pack2(ab.x, ab.y);
        }
    } else {
        const int lane = tid & 63;
        const int half = lane >> 5;
        const int hl = lane & 31;
        const int w0 = (bid - nbA) * 4 + (tid >> 6);
        const int npr = NP + 1;  // +1 virtual q row
        const int npairs = (npr + 1) >> 1;
        for (int w = w0; w < npairs; w += 12) {
            const int row = 2 * w + half;
            const bool valid = row < npr;
            const int rowc = valid ? row : NP;
            const bool isq = (rowc == NP);
            const int* ids = isq ? xs : (pers + (long)rowc * 20);
            const int L = isq ? LQ : 20;
            int myid = 0;
            if (hl < L) myid = ids[hl];
            float4 acc = {0.f, 0.f, 0.f, 0.f};
            for (int t = 0; t < L; ++t) {
                const int idx = __shfl(myid, (half << 5) + t, 64);
                const float4 e = *(const float4*)(semb + (long)idx * D + 4 * hl);
                acc.x += e.x; acc.y += e.y; acc.z += e.z; acc.w += e.w;
            }
            if (valid) {
                float* outp = isq ? st : (enc_pers + (long)rowc * D);
                *(float4*)(outp + 4 * hl) = acc;
                float sq = acc.x * acc.x + acc.y * acc.y + acc.z * acc.z + acc.w * acc.w;
                sq = halfwave_sum(sq);
                if (hl == 0) {
                    if (isq) st[384] = sqrtf(sq);
                    else pnorms[rowc] = sqrtf(sq);
                }
            }
        }
    }
}

// ===========================================================================
// persona hop device fn (runs on spare block of kvp_k, hidden under gather)
// ===========================================================================
__device__ void persona_dev(const float* __restrict__ pers_rows,
                            const float* __restrict__ pnorms,
                            const float* __restrict__ W, float* __restrict__ st,
                            int NP, float* smem, int tid) {
    float* qsh = smem;          // 128
    float* qh = smem + 128;     // 128
    float* att = smem + 256;    // 64
    float* red = smem + 320;    // 2
    if (tid < D) qsh[tid] = st[tid];
    __syncthreads();
    if (tid < NP) {
        float dot = 0.f;
        const float* pr = pers_rows + (long)tid * D;
        for (int d2 = 0; d2 < D; ++d2) dot += pr[d2] * qsh[d2];
        att[tid] = dot / fmaxf(pnorms[tid] * st[384], EPS);
    }
    __syncthreads();
    if (tid == 0) {
        float m = -1e30f;
        for (int p = 0; p < NP; ++p) m = fmaxf(m, att[p]);
        float s = 0.f;
        for (int p = 0; p < NP; ++p) { att[p] = __expf(att[p] - m); s += att[p]; }
        float inv = 1.f / s;
        for (int p = 0; p < NP; ++p) att[p] *= inv;
    }
    __syncthreads();
    if (tid < D) {
        float h = 0.f;
        for (int p = 0; p < NP; ++p) h += att[p] * pers_rows[(long)p * D + tid];
        qh[tid] = qsh[tid] + h;
    }
    __syncthreads();
    float qp = 0.f;
    if (tid < D) {
        for (int d2 = 0; d2 < D; ++d2) qp += W[(long)tid * D + d2] * qh[d2];
        st[128 + tid] = qp;
    }
    float sq = wave_sum(qp * qp);
    if ((tid & 63) == 0 && tid < 128) red[tid >> 6] = sq;
    __syncthreads();
    if (tid == 0) st[385] = sqrtf(red[0] + red[1]);
    if (tid < D) st[256 + tid] = 0.f;
    if (tid == 0) st[386] = 0.f;
}

// ===========================================================================
// kvp_k: single-pass-over-rows KV encode with ID-RANGE CHUNKING. Half-wave
// (32 lanes) owns a row; lane hl covers channels 4hl..4hl+3 (ushort4 = 256B
// contiguous per row request). Chunk pass c touches only ids in
// [cV/4,(c+1)V/4) — 3.2MB contiguous table region, L2-resident, full 128B
// line utilization. Ids + partial sums live in registers across all passes.
// Block 0: persona hop (depends only on prep, like KV).
// ===========================================================================
__global__ void kvp_k(const u16* __restrict__ tbl, const int* __restrict__ kids,
                      const int* __restrict__ vids, int N, int V,
                      u16* __restrict__ vb, float* __restrict__ knorms,
                      const float* __restrict__ enc_pers,
                      const float* __restrict__ pnorms,
                      const float* __restrict__ RW, float* __restrict__ st,
                      int NP) {
    __shared__ float smem[336];
    const int tid = threadIdx.x;
    const int bid = blockIdx.x;
    if (bid == 0) {
        persona_dev(enc_pers, pnorms, RW, st, NP, smem, tid);
        return;
    }
    const int lane = tid & 63;
    const int half = lane >> 5;
    const int hl = lane & 31;
    const int ghw = ((bid - 1) * 256 + tid) >> 5;   // global half-wave
    const int nhw = ((gridDim.x - 1) * 256) >> 5;
    for (int i = ghw; i < N; i += nhw) {
        int kid = 0, vid = 0;
        if (hl < 20) {
            kid = kids[(long)i * 20 + hl];
            vid = vids[(long)i * 20 + hl];
        }
        float k0 = 0.f, k1 = 0.f, k2 = 0.f, k3 = 0.f;
        float v0 = 0.f, v1 = 0.f, v2 = 0.f, v3 = 0.f;
#pragma unroll
        for (int c = 0; c < 4; ++c) {  // id-range chunks: 3.2MB L2-resident
            const int lo = (int)(((long)c * V) >> 2);
            const int hi = (c == 3) ? V : (int)(((long)(c + 1) * V) >> 2);
#pragma unroll
            for (int t = 0; t < 20; ++t) {
                const int kj = __shfl(kid, (half << 5) + t, 64);
                const int vj = __shfl(vid, (half << 5) + t, 64);
                if (kj >= lo && kj < hi) {  // uniform across half-wave
                    const ushort4 ke = *(const ushort4*)(tbl + (long)kj * D + 4 * hl);
                    k0 += bf2f(ke.x); k1 += bf2f(ke.y);
                    k2 += bf2f(ke.z); k3 += bf2f(ke.w);
                }
                if (vj >= lo && vj < hi) {
                    const ushort4 ve = *(const ushort4*)(tbl + (long)vj * D + 4 * hl);
                    v0 += bf2f(ve.x); v1 += bf2f(ve.y);
                    v2 += bf2f(ve.z); v3 += bf2f(ve.w);
                }
            }
        }
        uint2 pv;
        pv.x = pack2(v0, v1);
        pv.y = pack2(v2, v3);
        *(uint2*)(vb + (long)i * D + 4 * hl) = pv;
        float sq = halfwave_sum(k0 * k0 + k1 * k1 + k2 * k2 + k3 * k3);
        if (hl == 0) knorms[i] = sqrtf(sq);
    }
}

// ===========================================================================
// a2_k: s[v] = T16[v] . q_plus. Row-major: 64 lanes x uint = 256B contiguous.
// ===========================================================================
__global__ void a2_k(const u16* __restrict__ tbl, const float* __restrict__ st,
                     float* __restrict__ s, int V) {
    const int lane = threadIdx.x & 63;
    const float2 qp2 = *(const float2*)(st + 128 + 2 * lane);
    const int gw = (int)((blockIdx.x * blockDim.x + threadIdx.x) >> 6);
    const int nw = (int)((gridDim.x * blockDim.x) >> 6);
    for (int v = gw; v < V; v += nw) {
        const unsigned u = *(const unsigned*)(tbl + (long)v * D + 2 * lane);
        float d = bflo(u) * qp2.x + bfhi(u) * qp2.y;
        d = wave_sum(d);
        if (lane == 0) s[v] = d;
    }
}

// ===========================================================================
// attcv_k: fused b2e + cv. Half-wave per row: 20-lane sv gather -> dot ->
// e = exp(cos) in-register -> accumulate e * vb_row (row-major uint2).
// GRID <= 1024 BLOCKS (r10: ends in st atomics).
// ===========================================================================
__global__ void attcv_k(const float* __restrict__ sv, const int* __restrict__ kids,
                        const float* __restrict__ knorms, const u16* __restrict__ vb,
                        float* __restrict__ st, int N) {
    __shared__ float smem[129];
    const int tid = threadIdx.x;
    const int lane = tid & 63;
    const int half = lane >> 5;
    const int hl = lane & 31;
    const float qpn = st[385];
    const int ghw = (int)((blockIdx.x * blockDim.x + tid) >> 5);
    const int nhw = (int)((gridDim.x * blockDim.x) >> 5);
    float a0 = 0.f, a1 = 0.f, a2 = 0.f, a3 = 0.f;
    float esum = 0.f;
    for (int i = ghw; i < N; i += nhw) {
        float partial = 0.f;
        if (hl < 20) partial = sv[kids[(long)i * 20 + hl]];
        const float dot = halfwave_sum(partial);
        const float c = dot / fmaxf(knorms[i] * qpn, EPS);
        const float e = __expf(c);
        const uint2 vh = *(const uint2*)(vb + (long)i * D + 4 * hl);
        a0 += e * bflo(vh.x);
        a1 += e * bfhi(vh.x);
        a2 += e * bflo(vh.y);
        a3 += e * bfhi(vh.y);
        if (hl == 0) esum += e;
    }
    a0 += __shfl_xor(a0, 32, 64);
    a1 += __shfl_xor(a1, 32, 64);
    a2 += __shfl_xor(a2, 32, 64);
    a3 += __shfl_xor(a3, 32, 64);
    esum += __shfl_xor(esum, 32, 64);
    if (tid < 129) smem[tid] = 0.f;
    __syncthreads();
    if (half == 0) {
        atomicAdd(&smem[4 * hl + 0], a0);
        atomicAdd(&smem[4 * hl + 1], a1);
        atomicAdd(&smem[4 * hl + 2], a2);
        atomicAdd(&smem[4 * hl + 3], a3);
        if (hl == 0) atomicAdd(&smem[128], esum);
    }
    __syncthreads();
    if (tid < 128) atomicAdd(&st[256 + tid], smem[tid]);
    if (tid == 128) atomicAdd(&st[386], smem[128]);
}

// ===========================================================================
// mid_hop (1 block, 128 threads) — known-good.
// ===========================================================================
__global__ void mid_hop(const float* __restrict__ W1, const float* __restrict__ W2,
                        const float* __restrict__ pers_rows,
                        const float* __restrict__ pnorms,
                        float* __restrict__ st, int NP) {
    __shared__ float qh[D];
    __shared__ float qsh[D];
    __shared__ float att[64];
    __shared__ float red[2];
    int tid = threadIdx.x;
    float inv = 1.f / st[386];
    qh[tid] = st[128 + tid] + st[256 + tid] * inv;
    __syncthreads();
    float qn = 0.f;
    for (int d2 = 0; d2 < D; ++d2) qn += W1[tid * D + d2] * qh[d2];
    qsh[tid] = qn;
    st[tid] = qn;
    float sq = wave_sum(qn * qn);
    if ((tid & 63) == 0) red[tid >> 6] = sq;
    __syncthreads();
    float qnorm = sqrtf(red[0] + red[1]);
    if (tid == 0) st[384] = qnorm;
    if (tid < NP) {
        float dot = 0.f;
        for (int d2 = 0; d2 < D; ++d2) dot += pers_rows[tid * D + d2] * qsh[d2];
        att[tid] = dot / fmaxf(pnorms[tid] * qnorm, EPS);
    }
    __syncthreads();
    if (tid == 0) {
        float m = -1e30f;
        for (int p = 0; p < NP; ++p) m = fmaxf(m, att[p]);
        float s = 0.f;
        for (int p = 0; p < NP; ++p) { att[p] = __expf(att[p] - m); s += att[p]; }
        float is = 1.f / s;
        for (int p = 0; p < NP; ++p) att[p] *= is;
    }
    __syncthreads();
    float h = 0.f;
    for (int p = 0; p < NP; ++p) h += att[p] * pers_rows[p * D + tid];
    qh[tid] = qsh[tid] + h;
    __syncthreads();
    float qp = 0.f;
    for (int d2 = 0; d2 < D; ++d2) qp += W2[tid * D + d2] * qh[d2];
    st[128 + tid] = qp;
    float sq2 = wave_sum(qp * qp);
    if ((tid & 63) == 0) red[tid >> 6] = sq2;
    __syncthreads();
    if (tid == 0) st[385] = sqrtf(red[0] + red[1]);
    st[256 + tid] = 0.f;
    if (tid == 0) st[386] = 0.f;
}

// ===========================================================================
// k5f: finish-hop per-block in smem (removes a launch; W2 is L2-broadcast),
// then fp32 candidate gather + cosine (proven precision).
// ===========================================================================
__global__ void k5f(const float* __restrict__ W2, const float* __restrict__ cemb,
                    const int* __restrict__ cands, int NC,
                    const float* __restrict__ st, float* __restrict__ out) {
    __shared__ float qv[D];
    __shared__ float qhsh[D];
    __shared__ float red[2];
    __shared__ float qns;
    const int tid = threadIdx.x;
    // ---- finish-hop prologue (every block; deterministic identical result)
    const float inv = 1.f / st[386];
    if (tid < D) qhsh[tid] = st[128 + tid] + st[256 + tid] * inv;
    __syncthreads();
    float qn = 0.f;
    if (tid < D) {
        for (int d2 = 0; d2 < D; ++d2) qn += W2[(long)tid * D + d2] * qhsh[d2];
        qv[tid] = qn;
    }
    float sq = wave_sum(qn * qn);
    if ((tid & 63) == 0 && tid < 128) red[tid >> 6] = sq;
    __syncthreads();
    if (tid == 0) qns = sqrtf(red[0] + red[1]);
    __syncthreads();
    // ---- candidate gather + cosine
    const int lane = tid & 63;
    const int half = lane >> 5;
    const int hl = lane & 31;
    const int gw = (int)((blockIdx.x * blockDim.x + tid) >> 6);
    const int nw = (int)((gridDim.x * blockDim.x) >> 6);
    const float4 q4 = *(const float4*)(qv + 4 * hl);
    const float qnf = qns;
    const int npair = (NC + 1) >> 1;
    for (int p = gw; p < npair; p += nw) {
        const int row = 2 * p + half;
        const bool valid = row < NC;
        const int rowc = valid ? row : (NC - 1);
        int myid = 0;
        if (hl < 20) myid = cands[(long)rowc * 20 + hl];
        float4 acc = {0.f, 0.f, 0.f, 0.f};
#pragma unroll
        for (int t = 0; t < 20; ++t) {
            const int idx = __shfl(myid, (half << 5) + t, 64);
            const float4 e = *(const float4*)(cemb + (long)idx * D + 4 * hl);
            acc.x += e.x; acc.y += e.y; acc.z += e.z; acc.w += e.w;
        }
        float dot = halfwave_sum(acc.x * q4.x + acc.y * q4.y +
                                 acc.z * q4.z + acc.w * q4.w);
        float nsq = halfwave_sum(acc.x * acc.x + acc.y * acc.y +
                                 acc.z * acc.z + acc.w * acc.w);
        if (valid && hl == 0) out[row] = dot / fmaxf(sqrtf(nsq) * qnf, EPS);
    }
}

// ===========================================================================
// Fallback path kernels (no/undersized workspace): fp32 on-the-fly.
// ===========================================================================
__global__ void encode_small_p(const float* __restrict__ emb,
                               const int* __restrict__ pers, int NP, int LP,
                               const int* __restrict__ xs, int LQ,
                               float* __restrict__ pers_rows,
                               float* __restrict__ pnorms,
                               float* __restrict__ st) {
    const int lane = threadIdx.x & 63;
    const int half = lane >> 5;
    const int hl = lane & 31;
    int gw = (int)((blockIdx.x * blockDim.x + threadIdx.x) >> 6);
    int nw = (int)((gridDim.x * blockDim.x) >> 6);
    const int npr = NP + 1;
    const int npairs = (npr + 1) >> 1;
    for (int p = gw; p < npairs; p += nw) {
        const int row = 2 * p + half;
        const bool valid = row < npr;
        const int rowc = valid ? row : NP;
        const bool isq = (rowc == NP);
        const int* ids = isq ? xs : (pers + (long)rowc * LP);
        const int L = isq ? LQ : LP;
        int myid = 0;
        if (hl < L) myid = ids[hl];
        float4 acc = {0.f, 0.f, 0.f, 0.f};
        for (int t = 0; t < L; ++t) {
            const int idx = __shfl(myid, (half << 5) + t, 64);
            const float4 e = *(const float4*)(emb + (long)idx * D + 4 * hl);
            acc.x += e.x; acc.y += e.y; acc.z += e.z; acc.w += e.w;
        }
        if (valid) {
            float* outp = isq ? st : (pers_rows + (long)rowc * D);
            *(float4*)(outp + 4 * hl) = acc;
            float sq = acc.x * acc.x + acc.y * acc.y + acc.z * acc.z + acc.w * acc.w;
            sq = halfwave_sum(sq);
            if (hl == 0) {
                if (isq) st[384] = sqrtf(sq);
                else pnorms[rowc] = sqrtf(sq);
            }
        }
    }
}

__global__ void persona_hop(const float* __restrict__ pers_rows,
                            const float* __restrict__ pnorms,
                            const float* __restrict__ W,
                            float* __restrict__ st, int NP) {
    __shared__ float smem[336];
    persona_dev(pers_rows, pnorms, W, st, NP, smem, (int)threadIdx.x);
}

__global__ void finish_hop(const float* __restrict__ W, float* __restrict__ st) {
    __shared__ float qh[D];
    __shared__ float red[2];
    int tid = threadIdx.x;
    float inv = 1.f / st[386];
    qh[tid] = st[128 + tid] + st[256 + tid] * inv;
    __syncthreads();
    float qn = 0.f;
    for (int d2 = 0; d2 < D; ++d2) qn += W[tid * D + d2] * qh[d2];
    st[tid] = qn;
    float sq = wave_sum(qn * qn);
    if ((tid & 63) == 0) red[tid >> 6] = sq;
    __syncthreads();
    if (tid == 0) st[384] = sqrtf(red[0] + red[1]);
}

__global__ void k5_final(const float* __restrict__ cemb,
                         const int* __restrict__ cands, int NC,
                         const float* __restrict__ st, float* __restrict__ out) {
    const int lane = threadIdx.x & 63;
    const int half = lane >> 5;
    const int hl = lane & 31;
    const int gw = (int)((blockIdx.x * blockDim.x + threadIdx.x) >> 6);
    const int nw = (int)((gridDim.x * blockDim.x) >> 6);
    const float4 q4 = *(const float4*)(st + 4 * hl);
    const float qn = st[384];
    const int npair = (NC + 1) >> 1;
    for (int p = gw; p < npair; p += nw) {
        const int row = 2 * p + half;
        const bool valid = row < NC;
        const int rowc = valid ? row : (NC - 1);
        int myid = 0;
        if (hl < 20) myid = cands[(long)rowc * 20 + hl];
        float4 acc = {0.f, 0.f, 0.f, 0.f};
#pragma unroll
        for (int t = 0; t < 20; ++t) {
            const int idx = __shfl(myid, (half << 5) + t, 64);
            const float4 e = *(const float4*)(cemb + (long)idx * D + 4 * hl);
            acc.x += e.x; acc.y += e.y; acc.z += e.z; acc.w += e.w;
        }
        float dot = halfwave_sum(acc.x * q4.x + acc.y * q4.y +
                                 acc.z * q4.z + acc.w * q4.w);
        float nsq = halfwave_sum(acc.x * acc.x + acc.y * acc.y +
                                 acc.z * acc.z + acc.w * acc.w);
        if (valid && hl == 0) out[row] = dot / fmaxf(sqrtf(nsq) * qn, EPS);
    }
}

__global__ void big_att_rc(const float* __restrict__ emb,
                           const int* __restrict__ kids,
                           const int* __restrict__ vids,
                           float* __restrict__ st, int N) {
    __shared__ float s[129];
    const int tid = threadIdx.x;
    const int lane = tid & 63;
    const int half = lane >> 5;
    const int hl = lane & 31;
    const int gw = (int)((blockIdx.x * blockDim.x + tid) >> 6);
    const int nw = (int)((gridDim.x * blockDim.x) >> 6);
    const float4 qp = *(const float4*)(st + 128 + 4 * hl);
    const float qpn = st[385];
    float4 hacc = {0.f, 0.f, 0.f, 0.f};
    float esum = 0.f;
    const int npair = (N + 1) >> 1;
    for (int p = gw; p < npair; p += nw) {
        const int row = 2 * p + half;
        const bool valid = row < N;
        const int rowc = valid ? row : (N - 1);
        int kid = 0, vid = 0;
        if (hl < 20) {
            kid = kids[(long)rowc * 20 + hl];
            vid = vids[(long)rowc * 20 + hl];
        }
        float4 ka = {0.f, 0.f, 0.f, 0.f}, va = {0.f, 0.f, 0.f, 0.f};
#pragma unroll
        for (int t = 0; t < 20; ++t) {
            const int ki = __shfl(kid, (half << 5) + t, 64);
            const int vi = __shfl(vid, (half << 5) + t, 64);
            const float4 ke = *(const float4*)(emb + (long)ki * D + 4 * hl);
            const float4 ve = *(const float4*)(emb + (long)vi * D + 4 * hl);
            ka.x += ke.x; ka.y += ke.y; ka.z += ke.z; ka.w += ke.w;
            va.x += ve.x; va.y += ve.y; va.z += ve.z; va.w += ve.w;
        }
        float nsq = halfwave_sum(ka.x * ka.x + ka.y * ka.y + ka.z * ka.z + ka.w * ka.w);
        float dot = halfwave_sum(ka.x * qp.x + ka.y * qp.y + ka.z * qp.z + ka.w * qp.w);
        const float c = dot / fmaxf(sqrtf(nsq) * qpn, EPS);
        float e = __expf(c);
        if (!valid) e = 0.f;
        hacc.x += e * va.x; hacc.y += e * va.y;
        hacc.z += e * va.z; hacc.w += e * va.w;
        if (hl == 0) esum += e;
    }
    hacc.x += __shfl_xor(hacc.x, 32, 64);
    hacc.y += __shfl_xor(hacc.y, 32, 64);
    hacc.z += __shfl_xor(hacc.z, 32, 64);
    hacc.w += __shfl_xor(hacc.w, 32, 64);
    esum += __shfl_xor(esum, 32, 64);
    if (tid < 129) s[tid] = 0.f;
    __syncthreads();
    if (half == 0) {
        atomicAdd(&s[4 * hl + 0], hacc.x);
        atomicAdd(&s[4 * hl + 1], hacc.y);
        atomicAdd(&s[4 * hl + 2], hacc.z);
        atomicAdd(&s[4 * hl + 3], hacc.w);
        if (hl == 0) atomicAdd(&s[128], esum);
    }
    __syncthreads();
    if (tid < 128) atomicAdd(&st[256 + tid], s[tid]);
    if (tid == 128) atomicAdd(&st[386], s[128]);
}

static inline size_t align16(size_t b) { return (b + 15) & ~(size_t)15; }

extern "C" void kernel_launch(void* const* d_in, const int* in_sizes, int n_in,
                              void* d_out, int out_size, void* d_ws, size_t ws_size,
                              hipStream_t stream) {
    const int* xs = (const int*)d_in[0];
    const int* cands = (const int*)d_in[1];
    const int* pers = (const int*)d_in[2];
    const int* keys = (const int*)d_in[3];
    const int* values = (const int*)d_in[4];
    const float* semb = (const float*)d_in[6];
    const float* cemb = (const float*)d_in[7];
    const float* RW = (const float*)d_in[8];
    const float* R2W = (const float*)d_in[9];
    float* out = (float*)d_out;

    const int L = 20;
    const int LQ = in_sizes[0];
    const int VD = in_sizes[6];         // V*D (elements)
    const int V = VD / D;               // 50000
    const int NMEM = in_sizes[3] / L;   // 65536
    const int NCAND = in_sizes[1] / L;  // 10000
    const int NPERS = in_sizes[2] / L;  // 20

    size_t need = align16((size_t)VD * 2) + align16((size_t)NMEM * D * 2) +
                  align16((size_t)NMEM * 4) + align16((size_t)V * 4) +
                  align16((size_t)NPERS * D * 4) + align16((size_t)NPERS * 4) +
                  512 * 4;
    bool stored = (d_ws != nullptr) && (ws_size >= need) && (NMEM % 4 == 0) &&
                  (NMEM <= 65536) && ((VD & 3) == 0) && (LQ <= 32);

    const int THR = 256;
    char* base = (char*)d_ws;
    u16 *tbl16 = nullptr, *vb = nullptr;
    float *knorms = nullptr, *sv = nullptr;
    if (stored) {
        tbl16 = (u16*)base;  base += align16((size_t)VD * 2);        // row-major
        vb = (u16*)base;     base += align16((size_t)NMEM * D * 2);  // row-major
        knorms = (float*)base; base += align16((size_t)NMEM * 4);
        sv = (float*)base;   base += align16((size_t)V * 4);
    }
    float* enc_pers = (float*)base; base += align16((size_t)NPERS * D * 4);
    float* pnorms = (float*)base;   base += align16((size_t)NPERS * 4);
    float* st = (float*)base;

    if (stored) {
        const int nbA = 2048;
        // 1. prep: semb -> bf16 row-major || small encodes
        prep_k<<<nbA + 3, THR, 0, stream>>>(semb, tbl16, V, pers, NPERS, xs, LQ,
                                            enc_pers, pnorms, st, nbA);
        // 2. id-range-chunked KV encode (L2-resident 3.2MB chunks) || persona
        kvp_k<<<2049, THR, 0, stream>>>(tbl16, keys, values, NMEM, V, vb,
                                        knorms, enc_pers, pnorms, RW, st, NPERS);
        // 3-4. hop 1
        a2_k<<<2048, THR, 0, stream>>>(tbl16, st, sv, V);
        attcv_k<<<1024, THR, 0, stream>>>(sv, keys, knorms, vb, st, NMEM);  // r10
        // 5. mid hop
        mid_hop<<<1, 128, 0, stream>>>(RW, R2W, enc_pers, pnorms, st, NPERS);
        // 6-7. hop 2
        a2_k<<<2048, THR, 0, stream>>>(tbl16, st, sv, V);
        attcv_k<<<1024, THR, 0, stream>>>(sv, keys, knorms, vb, st, NMEM);  // r10
        // 8. finish-hop (per-block) + fp32 candidate gather
        int nblk5 = (((NCAND + 1) / 2) + 3) / 4;
        k5f<<<nblk5, THR, 0, stream>>>(R2W, cemb, cands, NCAND, st, out);
        (void)n_in; (void)out_size;
        return;
    }

    // -------- fallback: fp32 on-the-fly gather --------
    {
        int npairs = (NPERS + 2) / 2;
        int blocks = (npairs + 3) / 4;
        encode_small_p<<<blocks, THR, 0, stream>>>(semb, pers, NPERS, L, xs,
                                                   LQ, enc_pers, pnorms, st);
    }
    persona_hop<<<1, 128, 0, stream>>>(enc_pers, pnorms, RW, st, NPERS);
    big_att_rc<<<1024, THR, 0, stream>>>(semb, keys, values, st, NMEM);
    mid_hop<<<1, 128, 0, stream>>>(RW, R2W, enc_pers, pnorms, st, NPERS);
    big_att_rc<<<1024, THR, 0, stream>>>(semb, keys, values, st, NMEM);
    finish_hop<<<1, 128, 0, stream>>>(R2W, st);
    int nblk5 = (((NCAND + 1) / 2) + 3) / 4;
    k5_final<<<nblk5, THR, 0, stream>>>(cemb, cands, NCAND, st, out);

    (void)n_in; (void)out_size;
}

// Round 6
// 321.600 us; speedup vs baseline: 1.1736x; 1.1736x over previous
//
#include <hip/hip_runtime.h>
#include <math.h>
#include <stdint.h>

#define D 128
#define EPS 1e-6f
typedef unsigned short u16;

// ---------------------------------------------------------------------------
// state layout (floats), 16B-aligned base:
//   st[0..127]   : q            st[128..255] : q_plus (hop1 input)
//   st[256..383] : hop-1 acc    st[386]      : hop-1 sum-of-exp
//   st[512..639] : hop-2 acc    st[640]      : hop-2 sum-of-exp
//   st[384] ||q||   st[385] ||q_plus1||
// Rules: no device fences after bulk writes (r6); no global atomic scatters
// (r8); reducer grids <= 1024 blocks (r10); 1-block serial gathers are
// latency traps (r11); grid.sync >> launch gap (r14, 972us).
// r15/r17: gather FETCH model — contiguous >=128B-granular requests only.
// r19 (round 5): id-range chunking cut FETCH 233->172MB but DOUBLED time
// (140us, 1.4TB/s): 80 exec-mask-guarded iterations broke the back-to-back
// load stream. Gather time = max(FETCH/3.4TB/s, issue/latency); NEVER trade
// unconditional load streams for locality guards. Round-2 plain kvp (72us)
// is the keeper.
// r20 (this round): kill the ~240us non-KV chain structurally — kvp also
// stores kb[i]=sum_t T[kid_t] (fp32): hop dot becomes streaming kb.q_plus,
// deleting a2_k x2 and the 1.3M random sv gathers; mid_hop replicated
// per-block in smem (k5f-finish trick) with hop2 writing a second st bank.
// 5 launches total.
// ---------------------------------------------------------------------------

__device__ __forceinline__ float wave_sum(float v) {
#pragma unroll
    for (int off = 32; off > 0; off >>= 1) v += __shfl_xor(v, off, 64);
    return v;
}
__device__ __forceinline__ float halfwave_sum(float v) {
#pragma unroll
    for (int off = 16; off > 0; off >>= 1) v += __shfl_xor(v, off, 32);
    return v;
}

__device__ __forceinline__ float bf2f(u16 h) {
    union { unsigned u; float f; } x;
    x.u = ((unsigned)h) << 16;
    return x.f;
}
__device__ __forceinline__ float bflo(unsigned u) { return bf2f((u16)(u & 0xffff)); }
__device__ __forceinline__ float bfhi(unsigned u) { return bf2f((u16)(u >> 16)); }
__device__ __forceinline__ u16 f2bf(float f) {  // round-to-nearest-even
    union { float f; unsigned u; } x;
    x.f = f;
    unsigned u = x.u;
    return (u16)((u + 0x7fff + ((u >> 16) & 1)) >> 16);
}
__device__ __forceinline__ unsigned pack2(float a, float b) {
    return (unsigned)f2bf(a) | ((unsigned)f2bf(b) << 16);
}

// ===========================================================================
// prep_k: blocks [0,nbA) convert semb fp32 -> bf16 ROW-MAJOR; last 3 blocks
// do the small encodes (persona rows + q).
// ===========================================================================
__global__ void prep_k(const float* __restrict__ semb, u16* __restrict__ tbl,
                       int V, const int* __restrict__ pers, int NP,
                       const int* __restrict__ xs, int LQ,
                       float* __restrict__ enc_pers, float* __restrict__ pnorms,
                       float* __restrict__ st, int nbA) {
    const int tid = threadIdx.x;
    const int bid = blockIdx.x;
    if (bid < nbA) {
        const int n = V * 64;  // channel-pairs
        const int stride = nbA * 256;
        for (int i = bid * 256 + tid; i < n; i += stride) {
            const int v = i >> 6;
            const int c2 = i & 63;
            const float2 ab = *(const float2*)(semb + (long)v * D + 2 * c2);
            *(unsigned*)(tbl + (long)v * D + 2 * c2) = pack2(ab.x, ab.y);
        }
    } else {
        const int lane = tid & 63;
        const int half = lane >> 5;
        const int hl = lane & 31;
        const int w0 = (bid - nbA) * 4 + (tid >> 6);
        const int npr = NP + 1;  // +1 virtual q row
        const int npairs = (npr + 1) >> 1;
        for (int w = w0; w < npairs; w += 12) {
            const int row = 2 * w + half;
            const bool valid = row < npr;
            const int rowc = valid ? row : NP;
            const bool isq = (rowc == NP);
            const int* ids = isq ? xs : (pers + (long)rowc * 20);
            const int L = isq ? LQ : 20;
            int myid = 0;
            if (hl < L) myid = ids[hl];
            float4 acc = {0.f, 0.f, 0.f, 0.f};
            for (int t = 0; t < L; ++t) {
                const int idx = __shfl(myid, (half << 5) + t, 64);
                const float4 e = *(const float4*)(semb + (long)idx * D + 4 * hl);
                acc.x += e.x; acc.y += e.y; acc.z += e.z; acc.w += e.w;
            }
            if (valid) {
                float* outp = isq ? st : (enc_pers + (long)rowc * D);
                *(float4*)(outp + 4 * hl) = acc;
                float sq = acc.x * acc.x + acc.y * acc.y + acc.z * acc.z + acc.w * acc.w;
                sq = halfwave_sum(sq);
                if (hl == 0) {
                    if (isq) st[384] = sqrtf(sq);
                    else pnorms[rowc] = sqrtf(sq);
                }
            }
        }
    }
}

// ===========================================================================
// persona hop device fn (runs on block 0 of kvp_k, hidden under gather).
// Also zero-inits BOTH hop accumulator banks.
// ===========================================================================
__device__ void persona_dev(const float* __restrict__ pers_rows,
                            const float* __restrict__ pnorms,
                            const float* __restrict__ W, float* __restrict__ st,
                            int NP, float* smem, int tid) {
    float* qsh = smem;          // 128
    float* qh = smem + 128;     // 128
    float* att = smem + 256;    // 64
    float* red = smem + 320;    // 2
    if (tid < D) qsh[tid] = st[tid];
    __syncthreads();
    if (tid < NP) {
        float dot = 0.f;
        const float* pr = pers_rows + (long)tid * D;
        for (int d2 = 0; d2 < D; ++d2) dot += pr[d2] * qsh[d2];
        att[tid] = dot / fmaxf(pnorms[tid] * st[384], EPS);
    }
    __syncthreads();
    if (tid == 0) {
        float m = -1e30f;
        for (int p = 0; p < NP; ++p) m = fmaxf(m, att[p]);
        float s = 0.f;
        for (int p = 0; p < NP; ++p) { att[p] = __expf(att[p] - m); s += att[p]; }
        float inv = 1.f / s;
        for (int p = 0; p < NP; ++p) att[p] *= inv;
    }
    __syncthreads();
    if (tid < D) {
        float h = 0.f;
        for (int p = 0; p < NP; ++p) h += att[p] * pers_rows[(long)p * D + tid];
        qh[tid] = qsh[tid] + h;
    }
    __syncthreads();
    float qp = 0.f;
    if (tid < D) {
        for (int d2 = 0; d2 < D; ++d2) qp += W[(long)tid * D + d2] * qh[d2];
        st[128 + tid] = qp;
    }
    float sq = wave_sum(qp * qp);
    if ((tid & 63) == 0 && tid < 128) red[tid >> 6] = sq;
    __syncthreads();
    if (tid == 0) st[385] = sqrtf(red[0] + red[1]);
    if (tid < D) st[256 + tid] = 0.f;   // hop-1 acc
    if (tid < D) st[512 + tid] = 0.f;   // hop-2 acc
    if (tid == 0) { st[386] = 0.f; st[640] = 0.f; }
}

// ===========================================================================
// mid_dev_s: full mid-hop computed redundantly per block into SMEM ONLY.
// Reads st (qp1, acc1, esum1) + W1/W2/enc_pers/pnorms; writes qp_out[128],
// *qpn_out. Deterministic identical result in every block.
// ===========================================================================
__device__ void mid_dev_s(const float* __restrict__ W1, const float* __restrict__ W2,
                          const float* __restrict__ pers_rows,
                          const float* __restrict__ pnorms,
                          const float* __restrict__ st,
                          float* __restrict__ qp_out, float* __restrict__ qpn_out,
                          float* smem, int tid, int NP) {
    float* qh = smem;           // 128
    float* qsh = smem + 128;    // 128
    float* att = smem + 256;    // 64
    float* red = smem + 320;    // 2
    const float inv = 1.f / st[386];
    if (tid < D) qh[tid] = st[128 + tid] + st[256 + tid] * inv;
    __syncthreads();
    float qn = 0.f;
    if (tid < D) {
        for (int d2 = 0; d2 < D; ++d2) qn += W1[(long)tid * D + d2] * qh[d2];
        qsh[tid] = qn;
    }
    float sq = wave_sum(qn * qn);
    if ((tid & 63) == 0 && tid < 128) red[tid >> 6] = sq;
    __syncthreads();
    const float qnorm = sqrtf(red[0] + red[1]);
    if (tid < NP) {
        float dot = 0.f;
        for (int d2 = 0; d2 < D; ++d2) dot += pers_rows[(long)tid * D + d2] * qsh[d2];
        att[tid] = dot / fmaxf(pnorms[tid] * qnorm, EPS);
    }
    __syncthreads();
    if (tid == 0) {
        float m = -1e30f;
        for (int p = 0; p < NP; ++p) m = fmaxf(m, att[p]);
        float s = 0.f;
        for (int p = 0; p < NP; ++p) { att[p] = __expf(att[p] - m); s += att[p]; }
        float is = 1.f / s;
        for (int p = 0; p < NP; ++p) att[p] *= is;
    }
    __syncthreads();
    if (tid < D) {
        float h = 0.f;
        for (int p = 0; p < NP; ++p) h += att[p] * pers_rows[(long)p * D + tid];
        qh[tid] = qsh[tid] + h;
    }
    __syncthreads();
    float qp = 0.f;
    if (tid < D) {
        for (int d2 = 0; d2 < D; ++d2) qp += W2[(long)tid * D + d2] * qh[d2];
        qp_out[tid] = qp;
    }
    float sq2 = wave_sum(qp * qp);
    if ((tid & 63) == 0 && tid < 128) red[tid >> 6] = sq2;
    __syncthreads();
    if (tid == 0) *qpn_out = sqrtf(red[0] + red[1]);
    __syncthreads();
}

// ===========================================================================
// kvp_k: round-2 proven KV gather (72us) + kb store. Half-wave (32 lanes)
// owns a row; lane hl covers channels 4hl..4hl+3 (ushort4 = 256B contiguous
// per row request, unconditional back-to-back loads — r19). Writes
// kb fp32 (summed key vec), vb bf16, knorms. Block 0: persona hop.
// ===========================================================================
__global__ void kvp_k(const u16* __restrict__ tbl, const int* __restrict__ kids,
                      const int* __restrict__ vids, int N,
                      float* __restrict__ kb, u16* __restrict__ vb,
                      float* __restrict__ knorms,
                      const float* __restrict__ enc_pers,
                      const float* __restrict__ pnorms,
                      const float* __restrict__ RW, float* __restrict__ st,
                      int NP) {
    __shared__ float smem[336];
    const int tid = threadIdx.x;
    const int bid = blockIdx.x;
    if (bid == 0) {
        persona_dev(enc_pers, pnorms, RW, st, NP, smem, tid);
        return;
    }
    const int lane = tid & 63;
    const int half = lane >> 5;
    const int hl = lane & 31;
    const int ghw = ((bid - 1) * 256 + tid) >> 5;   // global half-wave
    const int nhw = ((gridDim.x - 1) * 256) >> 5;
    for (int i = ghw; i < N; i += nhw) {
        int kid = 0, vid = 0;
        if (hl < 20) {
            kid = kids[(long)i * 20 + hl];
            vid = vids[(long)i * 20 + hl];
        }
        float k0 = 0.f, k1 = 0.f, k2 = 0.f, k3 = 0.f;
        float v0 = 0.f, v1 = 0.f, v2 = 0.f, v3 = 0.f;
#pragma unroll
        for (int t = 0; t < 20; ++t) {
            const int kj = __shfl(kid, (half << 5) + t, 64);
            const int vj = __shfl(vid, (half << 5) + t, 64);
            const ushort4 ke = *(const ushort4*)(tbl + (long)kj * D + 4 * hl);
            const ushort4 ve = *(const ushort4*)(tbl + (long)vj * D + 4 * hl);
            k0 += bf2f(ke.x); k1 += bf2f(ke.y); k2 += bf2f(ke.z); k3 += bf2f(ke.w);
            v0 += bf2f(ve.x); v1 += bf2f(ve.y); v2 += bf2f(ve.z); v3 += bf2f(ve.w);
        }
        float4 kr;
        kr.x = k0; kr.y = k1; kr.z = k2; kr.w = k3;
        *(float4*)(kb + (long)i * D + 4 * hl) = kr;
        uint2 pv;
        pv.x = pack2(v0, v1);
        pv.y = pack2(v2, v3);
        *(uint2*)(vb + (long)i * D + 4 * hl) = pv;
        float sq = halfwave_sum(k0 * k0 + k1 * k1 + k2 * k2 + k3 * k3);
        if (hl == 0) knorms[i] = sqrtf(sq);
    }
}

// ===========================================================================
// attcv2_k: streaming attention hop — NO random gathers. Half-wave per row:
// dot = kb_row . q_plus (float4 loads, halfwave reduce), e = exp(cos),
// acc += e * vb_row. hop=0: q_plus from st; hop=1: per-block mid prologue.
// GRID <= 1024 BLOCKS (r10: ends in st atomics).
// ===========================================================================
__global__ void attcv2_k(const float* __restrict__ kb, const u16* __restrict__ vb,
                         const float* __restrict__ knorms,
                         const float* __restrict__ W1, const float* __restrict__ W2,
                         const float* __restrict__ enc_pers,
                         const float* __restrict__ pnorms,
                         float* __restrict__ st, int N, int NP, int hop) {
    __shared__ float msm[324];
    __shared__ float qp_s[128];
    __shared__ float qpn_s;
    __shared__ float rsm[129];
    const int tid = threadIdx.x;
    if (hop == 0) {
        if (tid < 128) qp_s[tid] = st[128 + tid];
        if (tid == 0) qpn_s = st[385];
    } else {
        mid_dev_s(W1, W2, enc_pers, pnorms, st, qp_s, &qpn_s, msm, tid, NP);
    }
    __syncthreads();
    const int lane = tid & 63;
    const int half = lane >> 5;
    const int hl = lane & 31;
    const float4 qp4 = *(const float4*)(qp_s + 4 * hl);
    const float qpn = qpn_s;
    const int aoff = hop ? 512 : 256;
    const int eoff = hop ? 640 : 386;
    const int ghw = (int)((blockIdx.x * blockDim.x + tid) >> 5);
    const int nhw = (int)((gridDim.x * blockDim.x) >> 5);
    float a0 = 0.f, a1 = 0.f, a2 = 0.f, a3 = 0.f;
    float esum = 0.f;
    for (int i = ghw; i < N; i += nhw) {
        const float4 kr = *(const float4*)(kb + (long)i * D + 4 * hl);
        const float part = kr.x * qp4.x + kr.y * qp4.y + kr.z * qp4.z + kr.w * qp4.w;
        const float dot = halfwave_sum(part);
        const float c = dot / fmaxf(knorms[i] * qpn, EPS);
        const float e = __expf(c);
        const uint2 vh = *(const uint2*)(vb + (long)i * D + 4 * hl);
        a0 += e * bflo(vh.x);
        a1 += e * bfhi(vh.x);
        a2 += e * bflo(vh.y);
        a3 += e * bfhi(vh.y);
        if (hl == 0) esum += e;
    }
    a0 += __shfl_xor(a0, 32, 64);
    a1 += __shfl_xor(a1, 32, 64);
    a2 += __shfl_xor(a2, 32, 64);
    a3 += __shfl_xor(a3, 32, 64);
    esum += __shfl_xor(esum, 32, 64);
    if (tid < 129) rsm[tid] = 0.f;
    __syncthreads();
    if (half == 0) {
        atomicAdd(&rsm[4 * hl + 0], a0);
        atomicAdd(&rsm[4 * hl + 1], a1);
        atomicAdd(&rsm[4 * hl + 2], a2);
        atomicAdd(&rsm[4 * hl + 3], a3);
        if (hl == 0) atomicAdd(&rsm[128], esum);
    }
    __syncthreads();
    if (tid < 128) atomicAdd(&st[aoff + tid], rsm[tid]);
    if (tid == 128) atomicAdd(&st[eoff], rsm[128]);
}

// ===========================================================================
// k5f: per-block mid + finish prologue in smem (no launches between hop2 and
// candidates), then fp32 candidate gather + cosine.
// ===========================================================================
__global__ void k5f(const float* __restrict__ W1, const float* __restrict__ W2,
                    const float* __restrict__ enc_pers,
                    const float* __restrict__ pnorms,
                    const float* __restrict__ cemb,
                    const int* __restrict__ cands, int NC, int NP,
                    const float* __restrict__ st, float* __restrict__ out) {
    __shared__ float msm[324];
    __shared__ float qp2_s[128];
    __shared__ float qpn2_s;
    __shared__ float qhf[128];
    __shared__ float qv[D];
    __shared__ float red2[2];
    __shared__ float qns;
    const int tid = threadIdx.x;
    mid_dev_s(W1, W2, enc_pers, pnorms, st, qp2_s, &qpn2_s, msm, tid, NP);
    // finish: q_final = W2 . (qp2 + acc2/esum2)
    const float inv2 = 1.f / st[640];
    if (tid < D) qhf[tid] = qp2_s[tid] + st[512 + tid] * inv2;
    __syncthreads();
    float qn = 0.f;
    if (tid < D) {
        for (int d2 = 0; d2 < D; ++d2) qn += W2[(long)tid * D + d2] * qhf[d2];
        qv[tid] = qn;
    }
    float sq = wave_sum(qn * qn);
    if ((tid & 63) == 0 && tid < 128) red2[tid >> 6] = sq;
    __syncthreads();
    if (tid == 0) qns = sqrtf(red2[0] + red2[1]);
    __syncthreads();
    // ---- candidate gather + cosine
    const int lane = tid & 63;
    const int half = lane >> 5;
    const int hl = lane & 31;
    const int gw = (int)((blockIdx.x * blockDim.x + tid) >> 6);
    const int nw = (int)((gridDim.x * blockDim.x) >> 6);
    const float4 q4 = *(const float4*)(qv + 4 * hl);
    const float qnf = qns;
    const int npair = (NC + 1) >> 1;
    for (int p = gw; p < npair; p += nw) {
        const int row = 2 * p + half;
        const bool valid = row < NC;
        const int rowc = valid ? row : (NC - 1);
        int myid = 0;
        if (hl < 20) myid = cands[(long)rowc * 20 + hl];
        float4 acc = {0.f, 0.f, 0.f, 0.f};
#pragma unroll
        for (int t = 0; t < 20; ++t) {
            const int idx = __shfl(myid, (half << 5) + t, 64);
            const float4 e = *(const float4*)(cemb + (long)idx * D + 4 * hl);
            acc.x += e.x; acc.y += e.y; acc.z += e.z; acc.w += e.w;
        }
        float dot = halfwave_sum(acc.x * q4.x + acc.y * q4.y +
                                 acc.z * q4.z + acc.w * q4.w);
        float nsq = halfwave_sum(acc.x * acc.x + acc.y * acc.y +
                                 acc.z * acc.z + acc.w * acc.w);
        if (valid && hl == 0) out[row] = dot / fmaxf(sqrtf(nsq) * qnf, EPS);
    }
}

// ===========================================================================
// Fallback path kernels (no/undersized workspace): fp32 on-the-fly.
// ===========================================================================
__global__ void encode_small_p(const float* __restrict__ emb,
                               const int* __restrict__ pers, int NP, int LP,
                               const int* __restrict__ xs, int LQ,
                               float* __restrict__ pers_rows,
                               float* __restrict__ pnorms,
                               float* __restrict__ st) {
    const int lane = threadIdx.x & 63;
    const int half = lane >> 5;
    const int hl = lane & 31;
    int gw = (int)((blockIdx.x * blockDim.x + threadIdx.x) >> 6);
    int nw = (int)((gridDim.x * blockDim.x) >> 6);
    const int npr = NP + 1;
    const int npairs = (npr + 1) >> 1;
    for (int p = gw; p < npairs; p += nw) {
        const int row = 2 * p + half;
        const bool valid = row < npr;
        const int rowc = valid ? row : NP;
        const bool isq = (rowc == NP);
        const int* ids = isq ? xs : (pers + (long)rowc * LP);
        const int L = isq ? LQ : LP;
        int myid = 0;
        if (hl < L) myid = ids[hl];
        float4 acc = {0.f, 0.f, 0.f, 0.f};
        for (int t = 0; t < L; ++t) {
            const int idx = __shfl(myid, (half << 5) + t, 64);
            const float4 e = *(const float4*)(emb + (long)idx * D + 4 * hl);
            acc.x += e.x; acc.y += e.y; acc.z += e.z; acc.w += e.w;
        }
        if (valid) {
            float* outp = isq ? st : (pers_rows + (long)rowc * D);
            *(float4*)(outp + 4 * hl) = acc;
            float sq = acc.x * acc.x + acc.y * acc.y + acc.z * acc.z + acc.w * acc.w;
            sq = halfwave_sum(sq);
            if (hl == 0) {
                if (isq) st[384] = sqrtf(sq);
                else pnorms[rowc] = sqrtf(sq);
            }
        }
    }
}

__global__ void persona_hop(const float* __restrict__ pers_rows,
                            const float* __restrict__ pnorms,
                            const float* __restrict__ W,
                            float* __restrict__ st, int NP) {
    __shared__ float smem[336];
    persona_dev(pers_rows, pnorms, W, st, NP, smem, (int)threadIdx.x);
}

__global__ void mid_hop(const float* __restrict__ W1, const float* __restrict__ W2,
                        const float* __restrict__ pers_rows,
                        const float* __restrict__ pnorms,
                        float* __restrict__ st, int NP) {
    __shared__ float qh[D];
    __shared__ float qsh[D];
    __shared__ float att[64];
    __shared__ float red[2];
    int tid = threadIdx.x;
    float inv = 1.f / st[386];
    qh[tid] = st[128 + tid] + st[256 + tid] * inv;
    __syncthreads();
    float qn = 0.f;
    for (int d2 = 0; d2 < D; ++d2) qn += W1[tid * D + d2] * qh[d2];
    qsh[tid] = qn;
    st[tid] = qn;
    float sq = wave_sum(qn * qn);
    if ((tid & 63) == 0) red[tid >> 6] = sq;
    __syncthreads();
    float qnorm = sqrtf(red[0] + red[1]);
    if (tid == 0) st[384] = qnorm;
    if (tid < NP) {
        float dot = 0.f;
        for (int d2 = 0; d2 < D; ++d2) dot += pers_rows[tid * D + d2] * qsh[d2];
        att[tid] = dot / fmaxf(pnorms[tid] * qnorm, EPS);
    }
    __syncthreads();
    if (tid == 0) {
        float m = -1e30f;
        for (int p = 0; p < NP; ++p) m = fmaxf(m, att[p]);
        float s = 0.f;
        for (int p = 0; p < NP; ++p) { att[p] = __expf(att[p] - m); s += att[p]; }
        float is = 1.f / s;
        for (int p = 0; p < NP; ++p) att[p] *= is;
    }
    __syncthreads();
    float h = 0.f;
    for (int p = 0; p < NP; ++p) h += att[p] * pers_rows[p * D + tid];
    qh[tid] = qsh[tid] + h;
    __syncthreads();
    float qp = 0.f;
    for (int d2 = 0; d2 < D; ++d2) qp += W2[tid * D + d2] * qh[d2];
    st[128 + tid] = qp;
    float sq2 = wave_sum(qp * qp);
    if ((tid & 63) == 0) red[tid >> 6] = sq2;
    __syncthreads();
    if (tid == 0) st[385] = sqrtf(red[0] + red[1]);
    st[256 + tid] = 0.f;
    if (tid == 0) st[386] = 0.f;
}

__global__ void finish_hop(const float* __restrict__ W, float* __restrict__ st) {
    __shared__ float qh[D];
    __shared__ float red[2];
    int tid = threadIdx.x;
    float inv = 1.f / st[386];
    qh[tid] = st[128 + tid] + st[256 + tid] * inv;
    __syncthreads();
    float qn = 0.f;
    for (int d2 = 0; d2 < D; ++d2) qn += W[tid * D + d2] * qh[d2];
    st[tid] = qn;
    float sq = wave_sum(qn * qn);
    if ((tid & 63) == 0) red[tid >> 6] = sq;
    __syncthreads();
    if (tid == 0) st[384] = sqrtf(red[0] + red[1]);
}

__global__ void k5_final(const float* __restrict__ cemb,
                         const int* __restrict__ cands, int NC,
                         const float* __restrict__ st, float* __restrict__ out) {
    const int lane = threadIdx.x & 63;
    const int half = lane >> 5;
    const int hl = lane & 31;
    const int gw = (int)((blockIdx.x * blockDim.x + threadIdx.x) >> 6);
    const int nw = (int)((gridDim.x * blockDim.x) >> 6);
    const float4 q4 = *(const float4*)(st + 4 * hl);
    const float qn = st[384];
    const int npair = (NC + 1) >> 1;
    for (int p = gw; p < npair; p += nw) {
        const int row = 2 * p + half;
        const bool valid = row < NC;
        const int rowc = valid ? row : (NC - 1);
        int myid = 0;
        if (hl < 20) myid = cands[(long)rowc * 20 + hl];
        float4 acc = {0.f, 0.f, 0.f, 0.f};
#pragma unroll
        for (int t = 0; t < 20; ++t) {
            const int idx = __shfl(myid, (half << 5) + t, 64);
            const float4 e = *(const float4*)(cemb + (long)idx * D + 4 * hl);
            acc.x += e.x; acc.y += e.y; acc.z += e.z; acc.w += e.w;
        }
        float dot = halfwave_sum(acc.x * q4.x + acc.y * q4.y +
                                 acc.z * q4.z + acc.w * q4.w);
        float nsq = halfwave_sum(acc.x * acc.x + acc.y * acc.y +
                                 acc.z * acc.z + acc.w * acc.w);
        if (valid && hl == 0) out[row] = dot / fmaxf(sqrtf(nsq) * qn, EPS);
    }
}

__global__ void big_att_rc(const float* __restrict__ emb,
                           const int* __restrict__ kids,
                           const int* __restrict__ vids,
                           float* __restrict__ st, int N) {
    __shared__ float s[129];
    const int tid = threadIdx.x;
    const int lane = tid & 63;
    const int half = lane >> 5;
    const int hl = lane & 31;
    const int gw = (int)((blockIdx.x * blockDim.x + tid) >> 6);
    const int nw = (int)((gridDim.x * blockDim.x) >> 6);
    const float4 qp = *(const float4*)(st + 128 + 4 * hl);
    const float qpn = st[385];
    float4 hacc = {0.f, 0.f, 0.f, 0.f};
    float esum = 0.f;
    const int npair = (N + 1) >> 1;
    for (int p = gw; p < npair; p += nw) {
        const int row = 2 * p + half;
        const bool valid = row < N;
        const int rowc = valid ? row : (N - 1);
        int kid = 0, vid = 0;
        if (hl < 20) {
            kid = kids[(long)rowc * 20 + hl];
            vid = vids[(long)rowc * 20 + hl];
        }
        float4 ka = {0.f, 0.f, 0.f, 0.f}, va = {0.f, 0.f, 0.f, 0.f};
#pragma unroll
        for (int t = 0; t < 20; ++t) {
            const int ki = __shfl(kid, (half << 5) + t, 64);
            const int vi = __shfl(vid, (half << 5) + t, 64);
            const float4 ke = *(const float4*)(emb + (long)ki * D + 4 * hl);
            const float4 ve = *(const float4*)(emb + (long)vi * D + 4 * hl);
            ka.x += ke.x; ka.y += ke.y; ka.z += ke.z; ka.w += ke.w;
            va.x += ve.x; va.y += ve.y; va.z += ve.z; va.w += ve.w;
        }
        float nsq = halfwave_sum(ka.x * ka.x + ka.y * ka.y + ka.z * ka.z + ka.w * ka.w);
        float dot = halfwave_sum(ka.x * qp.x + ka.y * qp.y + ka.z * qp.z + ka.w * qp.w);
        const float c = dot / fmaxf(sqrtf(nsq) * qpn, EPS);
        float e = __expf(c);
        if (!valid) e = 0.f;
        hacc.x += e * va.x; hacc.y += e * va.y;
        hacc.z += e * va.z; hacc.w += e * va.w;
        if (hl == 0) esum += e;
    }
    hacc.x += __shfl_xor(hacc.x, 32, 64);
    hacc.y += __shfl_xor(hacc.y, 32, 64);
    hacc.z += __shfl_xor(hacc.z, 32, 64);
    hacc.w += __shfl_xor(hacc.w, 32, 64);
    esum += __shfl_xor(esum, 32, 64);
    if (tid < 129) s[tid] = 0.f;
    __syncthreads();
    if (half == 0) {
        atomicAdd(&s[4 * hl + 0], hacc.x);
        atomicAdd(&s[4 * hl + 1], hacc.y);
        atomicAdd(&s[4 * hl + 2], hacc.z);
        atomicAdd(&s[4 * hl + 3], hacc.w);
        if (hl == 0) atomicAdd(&s[128], esum);
    }
    __syncthreads();
    if (tid < 128) atomicAdd(&st[256 + tid], s[tid]);
    if (tid == 128) atomicAdd(&st[386], s[128]);
}

static inline size_t align16(size_t b) { return (b + 15) & ~(size_t)15; }

extern "C" void kernel_launch(void* const* d_in, const int* in_sizes, int n_in,
                              void* d_out, int out_size, void* d_ws, size_t ws_size,
                              hipStream_t stream) {
    const int* xs = (const int*)d_in[0];
    const int* cands = (const int*)d_in[1];
    const int* pers = (const int*)d_in[2];
    const int* keys = (const int*)d_in[3];
    const int* values = (const int*)d_in[4];
    const float* semb = (const float*)d_in[6];
    const float* cemb = (const float*)d_in[7];
    const float* RW = (const float*)d_in[8];
    const float* R2W = (const float*)d_in[9];
    float* out = (float*)d_out;

    const int L = 20;
    const int LQ = in_sizes[0];
    const int VD = in_sizes[6];         // V*D (elements)
    const int V = VD / D;               // 50000
    const int NMEM = in_sizes[3] / L;   // 65536
    const int NCAND = in_sizes[1] / L;  // 10000
    const int NPERS = in_sizes[2] / L;  // 20

    size_t need = align16((size_t)VD * 2) + align16((size_t)NMEM * D * 2) +
                  align16((size_t)NMEM * D * 4) + align16((size_t)NMEM * 4) +
                  align16((size_t)NPERS * D * 4) + align16((size_t)NPERS * 4) +
                  1024 * 4;
    bool stored = (d_ws != nullptr) && (ws_size >= need) && (NMEM % 4 == 0) &&
                  (NMEM <= 65536) && ((VD & 3) == 0) && (LQ <= 32) &&
                  (NPERS <= 64);

    const int THR = 256;
    char* base = (char*)d_ws;
    u16 *tbl16 = nullptr, *vb = nullptr;
    float *kb = nullptr, *knorms = nullptr;
    if (stored) {
        tbl16 = (u16*)base;  base += align16((size_t)VD * 2);         // row-major
        vb = (u16*)base;     base += align16((size_t)NMEM * D * 2);   // row-major
        kb = (float*)base;   base += align16((size_t)NMEM * D * 4);   // fp32 key sums
        knorms = (float*)base; base += align16((size_t)NMEM * 4);
    }
    float* enc_pers = (float*)base; base += align16((size_t)NPERS * D * 4);
    float* pnorms = (float*)base;   base += align16((size_t)NPERS * 4);
    float* st = (float*)base;

    if (stored) {
        const int nbA = 2048;
        // 1. prep: semb -> bf16 row-major || small encodes
        prep_k<<<nbA + 3, THR, 0, stream>>>(semb, tbl16, V, pers, NPERS, xs, LQ,
                                            enc_pers, pnorms, st, nbA);
        // 2. KV gather (round-2 proven form) + kb store || persona hop (blk 0)
        kvp_k<<<2048, THR, 0, stream>>>(tbl16, keys, values, NMEM, kb, vb,
                                        knorms, enc_pers, pnorms, RW, st, NPERS);
        // 3. hop 1: streaming kb.qp -> e -> acc e*v      (r10: 1024 blocks)
        attcv2_k<<<1024, THR, 0, stream>>>(kb, vb, knorms, RW, R2W, enc_pers,
                                           pnorms, st, NMEM, NPERS, 0);
        // 4. hop 2: per-block mid prologue + same streaming pass
        attcv2_k<<<1024, THR, 0, stream>>>(kb, vb, knorms, RW, R2W, enc_pers,
                                           pnorms, st, NMEM, NPERS, 1);
        // 5. per-block mid+finish prologue + fp32 candidate gather
        k5f<<<640, THR, 0, stream>>>(RW, R2W, enc_pers, pnorms, cemb, cands,
                                     NCAND, NPERS, st, out);
        (void)n_in; (void)out_size;
        return;
    }

    // -------- fallback: fp32 on-the-fly gather --------
    {
        int npairs = (NPERS + 2) / 2;
        int blocks = (npairs + 3) / 4;
        encode_small_p<<<blocks, THR, 0, stream>>>(semb, pers, NPERS, L, xs,
                                                   LQ, enc_pers, pnorms, st);
    }
    persona_hop<<<1, 128, 0, stream>>>(enc_pers, pnorms, RW, st, NPERS);
    big_att_rc<<<1024, THR, 0, stream>>>(semb, keys, values, st, NMEM);
    mid_hop<<<1, 128, 0, stream>>>(RW, R2W, enc_pers, pnorms, st, NPERS);
    big_att_rc<<<1024, THR, 0, stream>>>(semb, keys, values, st, NMEM);
    finish_hop<<<1, 128, 0, stream>>>(R2W, st);
    int nblk5 = (((NCAND + 1) / 2) + 3) / 4;
    k5_final<<<nblk5, THR, 0, stream>>>(cemb, cands, NCAND, st, out);

    (void)n_in; (void)out_size;
}

// Round 7
// 269.102 us; speedup vs baseline: 1.4025x; 1.1951x over previous
//
#include <hip/hip_runtime.h>
#include <math.h>
#include <stdint.h>

#define D 128
#define EPS 1e-6f
typedef unsigned short u16;

#define NBK 16                    // reduction buckets (r21)
#define BSTR 132                  // bucket stride: 128 acc + 1 esum + pad
#define H1OFF 512                 // hop-1 bucket base in st
#define H2OFF (512 + NBK * BSTR)  // hop-2 bucket base (2624)

// ---------------------------------------------------------------------------
// st layout (floats): [0..127] q; [128..255] q_plus1; [384] ||q||;
// [385] ||q_plus1||; [H1OFF + b*BSTR + ch] hop-1 bucket b (ch 128 = esum);
// [H2OFF + ...] hop-2 buckets. (Old 256/386 fields kept for fallback only.)
// Rules: no global atomic scatters (r8); reducer grids <= 1024 (r10);
// 1-block serial gathers are latency traps (r11); grid.sync >> launch gap
// (r14); gather = max(FETCH/3.4TB/s, issue rate) — contiguous >=128B
// requests, never guarded load streams (r15/r17/r19).
// r20: kb[i]=sum_t T[kid_t] precomputed -> hops are streaming, a2/sv deleted.
// r21 (this round): non-KV time invariant ~245us across 15/8/5-launch
// structures — the cost hides below kvp in top-5. Suspect: 1024 blocks x
// 129-word same-address atomic tail (~1024 serialized line-atomics).
// Fix: 16-bucket staging (contention /16), consumers sum buckets. Also
// split kvp into kv_k/kv_v (~40us each) so the profile ceiling drops and
// the real #2 kernel finally surfaces.
// ---------------------------------------------------------------------------

__device__ __forceinline__ float wave_sum(float v) {
#pragma unroll
    for (int off = 32; off > 0; off >>= 1) v += __shfl_xor(v, off, 64);
    return v;
}
__device__ __forceinline__ float halfwave_sum(float v) {
#pragma unroll
    for (int off = 16; off > 0; off >>= 1) v += __shfl_xor(v, off, 32);
    return v;
}

__device__ __forceinline__ float bf2f(u16 h) {
    union { unsigned u; float f; } x;
    x.u = ((unsigned)h) << 16;
    return x.f;
}
__device__ __forceinline__ float bflo(unsigned u) { return bf2f((u16)(u & 0xffff)); }
__device__ __forceinline__ float bfhi(unsigned u) { return bf2f((u16)(u >> 16)); }
__device__ __forceinline__ u16 f2bf(float f) {  // round-to-nearest-even
    union { float f; unsigned u; } x;
    x.f = f;
    unsigned u = x.u;
    return (u16)((u + 0x7fff + ((u >> 16) & 1)) >> 16);
}
__device__ __forceinline__ unsigned pack2(float a, float b) {
    return (unsigned)f2bf(a) | ((unsigned)f2bf(b) << 16);
}

// ===========================================================================
// prep_k: blocks [0,nbA) convert semb fp32 -> bf16 ROW-MAJOR; last 3 blocks
// do the small encodes (persona rows + q).
// ===========================================================================
__global__ void prep_k(const float* __restrict__ semb, u16* __restrict__ tbl,
                       int V, const int* __restrict__ pers, int NP,
                       const int* __restrict__ xs, int LQ,
                       float* __restrict__ enc_pers, float* __restrict__ pnorms,
                       float* __restrict__ st, int nbA) {
    const int tid = threadIdx.x;
    const int bid = blockIdx.x;
    if (bid < nbA) {
        const int n = V * 64;  // channel-pairs
        const int stride = nbA * 256;
        for (int i = bid * 256 + tid; i < n; i += stride) {
            const int v = i >> 6;
            const int c2 = i & 63;
            const float2 ab = *(const float2*)(semb + (long)v * D + 2 * c2);
            *(unsigned*)(tbl + (long)v * D + 2 * c2) = pack2(ab.x, ab.y);
        }
    } else {
        const int lane = tid & 63;
        const int half = lane >> 5;
        const int hl = lane & 31;
        const int w0 = (bid - nbA) * 4 + (tid >> 6);
        const int npr = NP + 1;  // +1 virtual q row
        const int npairs = (npr + 1) >> 1;
        for (int w = w0; w < npairs; w += 12) {
            const int row = 2 * w + half;
            const bool valid = row < npr;
            const int rowc = valid ? row : NP;
            const bool isq = (rowc == NP);
            const int* ids = isq ? xs : (pers + (long)rowc * 20);
            const int L = isq ? LQ : 20;
            int myid = 0;
            if (hl < L) myid = ids[hl];
            float4 acc = {0.f, 0.f, 0.f, 0.f};
            for (int t = 0; t < L; ++t) {
                const int idx = __shfl(myid, (half << 5) + t, 64);
                const float4 e = *(const float4*)(semb + (long)idx * D + 4 * hl);
                acc.x += e.x; acc.y += e.y; acc.z += e.z; acc.w += e.w;
            }
            if (valid) {
                float* outp = isq ? st : (enc_pers + (long)rowc * D);
                *(float4*)(outp + 4 * hl) = acc;
                float sq = acc.x * acc.x + acc.y * acc.y + acc.z * acc.z + acc.w * acc.w;
                sq = halfwave_sum(sq);
                if (hl == 0) {
                    if (isq) st[384] = sqrtf(sq);
                    else pnorms[rowc] = sqrtf(sq);
                }
            }
        }
    }
}

// ===========================================================================
// persona hop device fn (runs on block 0 of kv_k, hidden under gather).
// zb=1: zero both hop bucket banks. zb=0 (fallback): zero old 256/386.
// ===========================================================================
__device__ void persona_dev(const float* __restrict__ pers_rows,
                            const float* __restrict__ pnorms,
                            const float* __restrict__ W, float* __restrict__ st,
                            int NP, float* smem, int tid, int zb) {
    float* qsh = smem;          // 128
    float* qh = smem + 128;     // 128
    float* att = smem + 256;    // 64
    float* red = smem + 320;    // 2
    if (tid < D) qsh[tid] = st[tid];
    __syncthreads();
    if (tid < NP) {
        float dot = 0.f;
        const float* pr = pers_rows + (long)tid * D;
        for (int d2 = 0; d2 < D; ++d2) dot += pr[d2] * qsh[d2];
        att[tid] = dot / fmaxf(pnorms[tid] * st[384], EPS);
    }
    __syncthreads();
    if (tid == 0) {
        float m = -1e30f;
        for (int p = 0; p < NP; ++p) m = fmaxf(m, att[p]);
        float s = 0.f;
        for (int p = 0; p < NP; ++p) { att[p] = __expf(att[p] - m); s += att[p]; }
        float inv = 1.f / s;
        for (int p = 0; p < NP; ++p) att[p] *= inv;
    }
    __syncthreads();
    if (tid < D) {
        float h = 0.f;
        for (int p = 0; p < NP; ++p) h += att[p] * pers_rows[(long)p * D + tid];
        qh[tid] = qsh[tid] + h;
    }
    __syncthreads();
    float qp = 0.f;
    if (tid < D) {
        for (int d2 = 0; d2 < D; ++d2) qp += W[(long)tid * D + d2] * qh[d2];
        st[128 + tid] = qp;
    }
    float sq = wave_sum(qp * qp);
    if ((tid & 63) == 0 && tid < 128) red[tid >> 6] = sq;
    __syncthreads();
    if (tid == 0) st[385] = sqrtf(red[0] + red[1]);
    if (zb) {
        for (int i = tid; i < 2 * NBK * BSTR; i += (int)blockDim.x)
            st[H1OFF + i] = 0.f;
    } else {
        if (tid < D) st[256 + tid] = 0.f;
        if (tid == 0) st[386] = 0.f;
    }
}

// ===========================================================================
// mid_dev_s: full mid-hop per block into SMEM only. acc1/esum1 from hop-1
// buckets. Writes qp_out[128], *qpn_out. Deterministic per block.
// ===========================================================================
__device__ void mid_dev_s(const float* __restrict__ W1, const float* __restrict__ W2,
                          const float* __restrict__ pers_rows,
                          const float* __restrict__ pnorms,
                          const float* __restrict__ st,
                          float* __restrict__ qp_out, float* __restrict__ qpn_out,
                          float* smem, int tid, int NP) {
    float* qh = smem;           // 128
    float* qsh = smem + 128;    // 128
    float* att = smem + 256;    // 64
    float* red = smem + 320;    // 2
    float esum = 0.f;
#pragma unroll
    for (int b = 0; b < NBK; ++b) esum += st[H1OFF + b * BSTR + 128];
    const float inv = 1.f / esum;
    if (tid < D) {
        float a = 0.f;
#pragma unroll
        for (int b = 0; b < NBK; ++b) a += st[H1OFF + b * BSTR + tid];
        qh[tid] = st[128 + tid] + a * inv;
    }
    __syncthreads();
    float qn = 0.f;
    if (tid < D) {
        for (int d2 = 0; d2 < D; ++d2) qn += W1[(long)tid * D + d2] * qh[d2];
        qsh[tid] = qn;
    }
    float sq = wave_sum(qn * qn);
    if ((tid & 63) == 0 && tid < 128) red[tid >> 6] = sq;
    __syncthreads();
    const float qnorm = sqrtf(red[0] + red[1]);
    if (tid < NP) {
        float dot = 0.f;
        for (int d2 = 0; d2 < D; ++d2) dot += pers_rows[(long)tid * D + d2] * qsh[d2];
        att[tid] = dot / fmaxf(pnorms[tid] * qnorm, EPS);
    }
    __syncthreads();
    if (tid == 0) {
        float m = -1e30f;
        for (int p = 0; p < NP; ++p) m = fmaxf(m, att[p]);
        float s = 0.f;
        for (int p = 0; p < NP; ++p) { att[p] = __expf(att[p] - m); s += att[p]; }
        float is = 1.f / s;
        for (int p = 0; p < NP; ++p) att[p] *= is;
    }
    __syncthreads();
    if (tid < D) {
        float h = 0.f;
        for (int p = 0; p < NP; ++p) h += att[p] * pers_rows[(long)p * D + tid];
        qh[tid] = qsh[tid] + h;
    }
    __syncthreads();
    float qp = 0.f;
    if (tid < D) {
        for (int d2 = 0; d2 < D; ++d2) qp += W2[(long)tid * D + d2] * qh[d2];
        qp_out[tid] = qp;
    }
    float sq2 = wave_sum(qp * qp);
    if ((tid & 63) == 0 && tid < 128) red[tid >> 6] = sq2;
    __syncthreads();
    if (tid == 0) *qpn_out = sqrtf(red[0] + red[1]);
    __syncthreads();
}

// ===========================================================================
// kv_k: key gather. Half-wave per row, ushort4 = 256B contiguous requests,
// unconditional back-to-back loads (r19). Writes kb fp32 + knorms.
// Block 0: persona hop (hidden under gather).
// ===========================================================================
__global__ void kv_k(const u16* __restrict__ tbl, const int* __restrict__ kids,
                     int N, float* __restrict__ kb, float* __restrict__ knorms,
                     const float* __restrict__ enc_pers,
                     const float* __restrict__ pnorms,
                     const float* __restrict__ RW, float* __restrict__ st,
                     int NP) {
    __shared__ float smem[336];
    const int tid = threadIdx.x;
    const int bid = blockIdx.x;
    if (bid == 0) {
        persona_dev(enc_pers, pnorms, RW, st, NP, smem, tid, 1);
        return;
    }
    const int lane = tid & 63;
    const int half = lane >> 5;
    const int hl = lane & 31;
    const int ghw = ((bid - 1) * 256 + tid) >> 5;
    const int nhw = ((gridDim.x - 1) * 256) >> 5;
    for (int i = ghw; i < N; i += nhw) {
        int kid = 0;
        if (hl < 20) kid = kids[(long)i * 20 + hl];
        float k0 = 0.f, k1 = 0.f, k2 = 0.f, k3 = 0.f;
#pragma unroll
        for (int t = 0; t < 20; ++t) {
            const int kj = __shfl(kid, (half << 5) + t, 64);
            const ushort4 ke = *(const ushort4*)(tbl + (long)kj * D + 4 * hl);
            k0 += bf2f(ke.x); k1 += bf2f(ke.y); k2 += bf2f(ke.z); k3 += bf2f(ke.w);
        }
        float4 kr;
        kr.x = k0; kr.y = k1; kr.z = k2; kr.w = k3;
        *(float4*)(kb + (long)i * D + 4 * hl) = kr;
        float sq = halfwave_sum(k0 * k0 + k1 * k1 + k2 * k2 + k3 * k3);
        if (hl == 0) knorms[i] = sqrtf(sq);
    }
}

// ===========================================================================
// kv_v: value gather. Same shape; writes vb bf16.
// ===========================================================================
__global__ void kv_v(const u16* __restrict__ tbl, const int* __restrict__ vids,
                     int N, u16* __restrict__ vb) {
    const int tid = threadIdx.x;
    const int bid = blockIdx.x;
    const int lane = tid & 63;
    const int half = lane >> 5;
    const int hl = lane & 31;
    const int ghw = (bid * 256 + tid) >> 5;
    const int nhw = (gridDim.x * 256) >> 5;
    for (int i = ghw; i < N; i += nhw) {
        int vid = 0;
        if (hl < 20) vid = vids[(long)i * 20 + hl];
        float v0 = 0.f, v1 = 0.f, v2 = 0.f, v3 = 0.f;
#pragma unroll
        for (int t = 0; t < 20; ++t) {
            const int vj = __shfl(vid, (half << 5) + t, 64);
            const ushort4 ve = *(const ushort4*)(tbl + (long)vj * D + 4 * hl);
            v0 += bf2f(ve.x); v1 += bf2f(ve.y); v2 += bf2f(ve.z); v3 += bf2f(ve.w);
        }
        uint2 pv;
        pv.x = pack2(v0, v1);
        pv.y = pack2(v2, v3);
        *(uint2*)(vb + (long)i * D + 4 * hl) = pv;
    }
}

// ===========================================================================
// attcv2_k: streaming hop. dot = kb_row . q_plus, e = exp(cos), acc += e*vb.
// Tail: 16-bucket staged atomics (r21) — contention /16 vs single target.
// hop=0: q_plus from st; hop=1: per-block mid prologue.
// GRID <= 1024 (r10).
// ===========================================================================
__global__ void attcv2_k(const float* __restrict__ kb, const u16* __restrict__ vb,
                         const float* __restrict__ knorms,
                         const float* __restrict__ W1, const float* __restrict__ W2,
                         const float* __restrict__ enc_pers,
                         const float* __restrict__ pnorms,
                         float* __restrict__ st, int N, int NP, int hop) {
    __shared__ float msm[324];
    __shared__ float qp_s[128];
    __shared__ float qpn_s;
    __shared__ float rsm[129];
    const int tid = threadIdx.x;
    if (hop == 0) {
        if (tid < 128) qp_s[tid] = st[128 + tid];
        if (tid == 0) qpn_s = st[385];
    } else {
        mid_dev_s(W1, W2, enc_pers, pnorms, st, qp_s, &qpn_s, msm, tid, NP);
    }
    __syncthreads();
    const int lane = tid & 63;
    const int half = lane >> 5;
    const int hl = lane & 31;
    const float4 qp4 = *(const float4*)(qp_s + 4 * hl);
    const float qpn = qpn_s;
    const int aoff = (hop ? H2OFF : H1OFF) + (int)(blockIdx.x & (NBK - 1)) * BSTR;
    const int ghw = (int)((blockIdx.x * blockDim.x + tid) >> 5);
    const int nhw = (int)((gridDim.x * blockDim.x) >> 5);
    float a0 = 0.f, a1 = 0.f, a2 = 0.f, a3 = 0.f;
    float esum = 0.f;
    for (int i = ghw; i < N; i += nhw) {
        const float4 kr = *(const float4*)(kb + (long)i * D + 4 * hl);
        const float part = kr.x * qp4.x + kr.y * qp4.y + kr.z * qp4.z + kr.w * qp4.w;
        const float dot = halfwave_sum(part);
        const float c = dot / fmaxf(knorms[i] * qpn, EPS);
        const float e = __expf(c);
        const uint2 vh = *(const uint2*)(vb + (long)i * D + 4 * hl);
        a0 += e * bflo(vh.x);
        a1 += e * bfhi(vh.x);
        a2 += e * bflo(vh.y);
        a3 += e * bfhi(vh.y);
        if (hl == 0) esum += e;
    }
    a0 += __shfl_xor(a0, 32, 64);
    a1 += __shfl_xor(a1, 32, 64);
    a2 += __shfl_xor(a2, 32, 64);
    a3 += __shfl_xor(a3, 32, 64);
    esum += __shfl_xor(esum, 32, 64);
    if (tid < 129) rsm[tid] = 0.f;
    __syncthreads();
    if (half == 0) {
        atomicAdd(&rsm[4 * hl + 0], a0);
        atomicAdd(&rsm[4 * hl + 1], a1);
        atomicAdd(&rsm[4 * hl + 2], a2);
        atomicAdd(&rsm[4 * hl + 3], a3);
        if (hl == 0) atomicAdd(&rsm[128], esum);
    }
    __syncthreads();
    if (tid < 128) atomicAdd(&st[aoff + tid], rsm[tid]);
    if (tid == 128) atomicAdd(&st[aoff + 128], rsm[128]);
}

// ===========================================================================
// k5f: per-block mid + finish prologue (finish reads hop-2 buckets), then
// fp32 candidate gather + cosine.
// ===========================================================================
__global__ void k5f(const float* __restrict__ W1, const float* __restrict__ W2,
                    const float* __restrict__ enc_pers,
                    const float* __restrict__ pnorms,
                    const float* __restrict__ cemb,
                    const int* __restrict__ cands, int NC, int NP,
                    const float* __restrict__ st, float* __restrict__ out) {
    __shared__ float msm[324];
    __shared__ float qp2_s[128];
    __shared__ float qpn2_s;
    __shared__ float qhf[128];
    __shared__ float qv[D];
    __shared__ float red2[2];
    __shared__ float qns;
    const int tid = threadIdx.x;
    mid_dev_s(W1, W2, enc_pers, pnorms, st, qp2_s, &qpn2_s, msm, tid, NP);
    float esum2 = 0.f;
#pragma unroll
    for (int b = 0; b < NBK; ++b) esum2 += st[H2OFF + b * BSTR + 128];
    const float inv2 = 1.f / esum2;
    if (tid < D) {
        float a = 0.f;
#pragma unroll
        for (int b = 0; b < NBK; ++b) a += st[H2OFF + b * BSTR + tid];
        qhf[tid] = qp2_s[tid] + a * inv2;
    }
    __syncthreads();
    float qn = 0.f;
    if (tid < D) {
        for (int d2 = 0; d2 < D; ++d2) qn += W2[(long)tid * D + d2] * qhf[d2];
        qv[tid] = qn;
    }
    float sq = wave_sum(qn * qn);
    if ((tid & 63) == 0 && tid < 128) red2[tid >> 6] = sq;
    __syncthreads();
    if (tid == 0) qns = sqrtf(red2[0] + red2[1]);
    __syncthreads();
    // ---- candidate gather + cosine
    const int lane = tid & 63;
    const int half = lane >> 5;
    const int hl = lane & 31;
    const int gw = (int)((blockIdx.x * blockDim.x + tid) >> 6);
    const int nw = (int)((gridDim.x * blockDim.x) >> 6);
    const float4 q4 = *(const float4*)(qv + 4 * hl);
    const float qnf = qns;
    const int npair = (NC + 1) >> 1;
    for (int p = gw; p < npair; p += nw) {
        const int row = 2 * p + half;
        const bool valid = row < NC;
        const int rowc = valid ? row : (NC - 1);
        int myid = 0;
        if (hl < 20) myid = cands[(long)rowc * 20 + hl];
        float4 acc = {0.f, 0.f, 0.f, 0.f};
#pragma unroll
        for (int t = 0; t < 20; ++t) {
            const int idx = __shfl(myid, (half << 5) + t, 64);
            const float4 e = *(const float4*)(cemb + (long)idx * D + 4 * hl);
            acc.x += e.x; acc.y += e.y; acc.z += e.z; acc.w += e.w;
        }
        float dot = halfwave_sum(acc.x * q4.x + acc.y * q4.y +
                                 acc.z * q4.z + acc.w * q4.w);
        float nsq = halfwave_sum(acc.x * acc.x + acc.y * acc.y +
                                 acc.z * acc.z + acc.w * acc.w);
        if (valid && hl == 0) out[row] = dot / fmaxf(sqrtf(nsq) * qnf, EPS);
    }
}

// ===========================================================================
// Fallback path kernels (no/undersized workspace): fp32 on-the-fly.
// ===========================================================================
__global__ void encode_small_p(const float* __restrict__ emb,
                               const int* __restrict__ pers, int NP, int LP,
                               const int* __restrict__ xs, int LQ,
                               float* __restrict__ pers_rows,
                               float* __restrict__ pnorms,
                               float* __restrict__ st) {
    const int lane = threadIdx.x & 63;
    const int half = lane >> 5;
    const int hl = lane & 31;
    int gw = (int)((blockIdx.x * blockDim.x + threadIdx.x) >> 6);
    int nw = (int)((gridDim.x * blockDim.x) >> 6);
    const int npr = NP + 1;
    const int npairs = (npr + 1) >> 1;
    for (int p = gw; p < npairs; p += nw) {
        const int row = 2 * p + half;
        const bool valid = row < npr;
        const int rowc = valid ? row : NP;
        const bool isq = (rowc == NP);
        const int* ids = isq ? xs : (pers + (long)rowc * LP);
        const int L = isq ? LQ : LP;
        int myid = 0;
        if (hl < L) myid = ids[hl];
        float4 acc = {0.f, 0.f, 0.f, 0.f};
        for (int t = 0; t < L; ++t) {
            const int idx = __shfl(myid, (half << 5) + t, 64);
            const float4 e = *(const float4*)(emb + (long)idx * D + 4 * hl);
            acc.x += e.x; acc.y += e.y; acc.z += e.z; acc.w += e.w;
        }
        if (valid) {
            float* outp = isq ? st : (pers_rows + (long)rowc * D);
            *(float4*)(outp + 4 * hl) = acc;
            float sq = acc.x * acc.x + acc.y * acc.y + acc.z * acc.z + acc.w * acc.w;
            sq = halfwave_sum(sq);
            if (hl == 0) {
                if (isq) st[384] = sqrtf(sq);
                else pnorms[rowc] = sqrtf(sq);
            }
        }
    }
}

__global__ void persona_hop(const float* __restrict__ pers_rows,
                            const float* __restrict__ pnorms,
                            const float* __restrict__ W,
                            float* __restrict__ st, int NP) {
    __shared__ float smem[336];
    persona_dev(pers_rows, pnorms, W, st, NP, smem, (int)threadIdx.x, 0);
}

__global__ void mid_hop(const float* __restrict__ W1, const float* __restrict__ W2,
                        const float* __restrict__ pers_rows,
                        const float* __restrict__ pnorms,
                        float* __restrict__ st, int NP) {
    __shared__ float qh[D];
    __shared__ float qsh[D];
    __shared__ float att[64];
    __shared__ float red[2];
    int tid = threadIdx.x;
    float inv = 1.f / st[386];
    qh[tid] = st[128 + tid] + st[256 + tid] * inv;
    __syncthreads();
    float qn = 0.f;
    for (int d2 = 0; d2 < D; ++d2) qn += W1[tid * D + d2] * qh[d2];
    qsh[tid] = qn;
    st[tid] = qn;
    float sq = wave_sum(qn * qn);
    if ((tid & 63) == 0) red[tid >> 6] = sq;
    __syncthreads();
    float qnorm = sqrtf(red[0] + red[1]);
    if (tid == 0) st[384] = qnorm;
    if (tid < NP) {
        float dot = 0.f;
        for (int d2 = 0; d2 < D; ++d2) dot += pers_rows[tid * D + d2] * qsh[d2];
        att[tid] = dot / fmaxf(pnorms[tid] * qnorm, EPS);
    }
    __syncthreads();
    if (tid == 0) {
        float m = -1e30f;
        for (int p = 0; p < NP; ++p) m = fmaxf(m, att[p]);
        float s = 0.f;
        for (int p = 0; p < NP; ++p) { att[p] = __expf(att[p] - m); s += att[p]; }
        float is = 1.f / s;
        for (int p = 0; p < NP; ++p) att[p] *= is;
    }
    __syncthreads();
    float h = 0.f;
    for (int p = 0; p < NP; ++p) h += att[p] * pers_rows[p * D + tid];
    qh[tid] = qsh[tid] + h;
    __syncthreads();
    float qp = 0.f;
    for (int d2 = 0; d2 < D; ++d2) qp += W2[tid * D + d2] * qh[d2];
    st[128 + tid] = qp;
    float sq2 = wave_sum(qp * qp);
    if ((tid & 63) == 0) red[tid >> 6] = sq2;
    __syncthreads();
    if (tid == 0) st[385] = sqrtf(red[0] + red[1]);
    st[256 + tid] = 0.f;
    if (tid == 0) st[386] = 0.f;
}

__global__ void finish_hop(const float* __restrict__ W, float* __restrict__ st) {
    __shared__ float qh[D];
    __shared__ float red[2];
    int tid = threadIdx.x;
    float inv = 1.f / st[386];
    qh[tid] = st[128 + tid] + st[256 + tid] * inv;
    __syncthreads();
    float qn = 0.f;
    for (int d2 = 0; d2 < D; ++d2) qn += W[tid * D + d2] * qh[d2];
    st[tid] = qn;
    float sq = wave_sum(qn * qn);
    if ((tid & 63) == 0) red[tid >> 6] = sq;
    __syncthreads();
    if (tid == 0) st[384] = sqrtf(red[0] + red[1]);
}

__global__ void k5_final(const float* __restrict__ cemb,
                         const int* __restrict__ cands, int NC,
                         const float* __restrict__ st, float* __restrict__ out) {
    const int lane = threadIdx.x & 63;
    const int half = lane >> 5;
    const int hl = lane & 31;
    const int gw = (int)((blockIdx.x * blockDim.x + threadIdx.x) >> 6);
    const int nw = (int)((gridDim.x * blockDim.x) >> 6);
    const float4 q4 = *(const float4*)(st + 4 * hl);
    const float qn = st[384];
    const int npair = (NC + 1) >> 1;
    for (int p = gw; p < npair; p += nw) {
        const int row = 2 * p + half;
        const bool valid = row < NC;
        const int rowc = valid ? row : (NC - 1);
        int myid = 0;
        if (hl < 20) myid = cands[(long)rowc * 20 + hl];
        float4 acc = {0.f, 0.f, 0.f, 0.f};
#pragma unroll
        for (int t = 0; t < 20; ++t) {
            const int idx = __shfl(myid, (half << 5) + t, 64);
            const float4 e = *(const float4*)(cemb + (long)idx * D + 4 * hl);
            acc.x += e.x; acc.y += e.y; acc.z += e.z; acc.w += e.w;
        }
        float dot = halfwave_sum(acc.x * q4.x + acc.y * q4.y +
                                 acc.z * q4.z + acc.w * q4.w);
        float nsq = halfwave_sum(acc.x * acc.x + acc.y * acc.y +
                                 acc.z * acc.z + acc.w * acc.w);
        if (valid && hl == 0) out[row] = dot / fmaxf(sqrtf(nsq) * qn, EPS);
    }
}

__global__ void big_att_rc(const float* __restrict__ emb,
                           const int* __restrict__ kids,
                           const int* __restrict__ vids,
                           float* __restrict__ st, int N) {
    __shared__ float s[129];
    const int tid = threadIdx.x;
    const int lane = tid & 63;
    const int half = lane >> 5;
    const int hl = lane & 31;
    const int gw = (int)((blockIdx.x * blockDim.x + tid) >> 6);
    const int nw = (int)((gridDim.x * blockDim.x) >> 6);
    const float4 qp = *(const float4*)(st + 128 + 4 * hl);
    const float qpn = st[385];
    float4 hacc = {0.f, 0.f, 0.f, 0.f};
    float esum = 0.f;
    const int npair = (N + 1) >> 1;
    for (int p = gw; p < npair; p += nw) {
        const int row = 2 * p + half;
        const bool valid = row < N;
        const int rowc = valid ? row : (N - 1);
        int kid = 0, vid = 0;
        if (hl < 20) {
            kid = kids[(long)rowc * 20 + hl];
            vid = vids[(long)rowc * 20 + hl];
        }
        float4 ka = {0.f, 0.f, 0.f, 0.f}, va = {0.f, 0.f, 0.f, 0.f};
#pragma unroll
        for (int t = 0; t < 20; ++t) {
            const int ki = __shfl(kid, (half << 5) + t, 64);
            const int vi = __shfl(vid, (half << 5) + t, 64);
            const float4 ke = *(const float4*)(emb + (long)ki * D + 4 * hl);
            const float4 ve = *(const float4*)(emb + (long)vi * D + 4 * hl);
            ka.x += ke.x; ka.y += ke.y; ka.z += ke.z; ka.w += ke.w;
            va.x += ve.x; va.y += ve.y; va.z += ve.z; va.w += ve.w;
        }
        float nsq = halfwave_sum(ka.x * ka.x + ka.y * ka.y + ka.z * ka.z + ka.w * ka.w);
        float dot = halfwave_sum(ka.x * qp.x + ka.y * qp.y + ka.z * qp.z + ka.w * qp.w);
        const float c = dot / fmaxf(sqrtf(nsq) * qpn, EPS);
        float e = __expf(c);
        if (!valid) e = 0.f;
        hacc.x += e * va.x; hacc.y += e * va.y;
        hacc.z += e * va.z; hacc.w += e * va.w;
        if (hl == 0) esum += e;
    }
    hacc.x += __shfl_xor(hacc.x, 32, 64);
    hacc.y += __shfl_xor(hacc.y, 32, 64);
    hacc.z += __shfl_xor(hacc.z, 32, 64);
    hacc.w += __shfl_xor(hacc.w, 32, 64);
    esum += __shfl_xor(esum, 32, 64);
    if (tid < 129) s[tid] = 0.f;
    __syncthreads();
    if (half == 0) {
        atomicAdd(&s[4 * hl + 0], hacc.x);
        atomicAdd(&s[4 * hl + 1], hacc.y);
        atomicAdd(&s[4 * hl + 2], hacc.z);
        atomicAdd(&s[4 * hl + 3], hacc.w);
        if (hl == 0) atomicAdd(&s[128], esum);
    }
    __syncthreads();
    if (tid < 128) atomicAdd(&st[256 + tid], s[tid]);
    if (tid == 128) atomicAdd(&st[386], s[128]);
}

static inline size_t align16(size_t b) { return (b + 15) & ~(size_t)15; }

extern "C" void kernel_launch(void* const* d_in, const int* in_sizes, int n_in,
                              void* d_out, int out_size, void* d_ws, size_t ws_size,
                              hipStream_t stream) {
    const int* xs = (const int*)d_in[0];
    const int* cands = (const int*)d_in[1];
    const int* pers = (const int*)d_in[2];
    const int* keys = (const int*)d_in[3];
    const int* values = (const int*)d_in[4];
    const float* semb = (const float*)d_in[6];
    const float* cemb = (const float*)d_in[7];
    const float* RW = (const float*)d_in[8];
    const float* R2W = (const float*)d_in[9];
    float* out = (float*)d_out;

    const int L = 20;
    const int LQ = in_sizes[0];
    const int VD = in_sizes[6];         // V*D (elements)
    const int V = VD / D;               // 50000
    const int NMEM = in_sizes[3] / L;   // 65536
    const int NCAND = in_sizes[1] / L;  // 10000
    const int NPERS = in_sizes[2] / L;  // 20

    size_t need = align16((size_t)VD * 2) + align16((size_t)NMEM * D * 2) +
                  align16((size_t)NMEM * D * 4) + align16((size_t)NMEM * 4) +
                  align16((size_t)NPERS * D * 4) + align16((size_t)NPERS * 4) +
                  8192 * 4;
    bool stored = (d_ws != nullptr) && (ws_size >= need) && (NMEM % 4 == 0) &&
                  (NMEM <= 65536) && ((VD & 3) == 0) && (LQ <= 32) &&
                  (NPERS <= 64);

    const int THR = 256;
    char* base = (char*)d_ws;
    u16 *tbl16 = nullptr, *vb = nullptr;
    float *kb = nullptr, *knorms = nullptr;
    if (stored) {
        tbl16 = (u16*)base;  base += align16((size_t)VD * 2);         // row-major
        vb = (u16*)base;     base += align16((size_t)NMEM * D * 2);   // row-major
        kb = (float*)base;   base += align16((size_t)NMEM * D * 4);   // fp32 key sums
        knorms = (float*)base; base += align16((size_t)NMEM * 4);
    }
    float* enc_pers = (float*)base; base += align16((size_t)NPERS * D * 4);
    float* pnorms = (float*)base;   base += align16((size_t)NPERS * 4);
    float* st = (float*)base;

    if (stored) {
        const int nbA = 2048;
        // 1. prep: semb -> bf16 row-major || small encodes
        prep_k<<<nbA + 3, THR, 0, stream>>>(semb, tbl16, V, pers, NPERS, xs, LQ,
                                            enc_pers, pnorms, st, nbA);
        // 2. key gather -> kb fp32 + knorms || persona hop (block 0)
        kv_k<<<2049, THR, 0, stream>>>(tbl16, keys, NMEM, kb, knorms,
                                       enc_pers, pnorms, RW, st, NPERS);
        // 3. value gather -> vb bf16
        kv_v<<<2048, THR, 0, stream>>>(tbl16, values, NMEM, vb);
        // 4. hop 1: streaming kb.qp -> e -> acc e*v (bucketed reduce, r21)
        attcv2_k<<<1024, THR, 0, stream>>>(kb, vb, knorms, RW, R2W, enc_pers,
                                           pnorms, st, NMEM, NPERS, 0);
        // 5. hop 2: per-block mid prologue + same streaming pass
        attcv2_k<<<1024, THR, 0, stream>>>(kb, vb, knorms, RW, R2W, enc_pers,
                                           pnorms, st, NMEM, NPERS, 1);
        // 6. per-block mid+finish prologue + fp32 candidate gather
        k5f<<<640, THR, 0, stream>>>(RW, R2W, enc_pers, pnorms, cemb, cands,
                                     NCAND, NPERS, st, out);
        (void)n_in; (void)out_size;
        return;
    }

    // -------- fallback: fp32 on-the-fly gather --------
    {
        int npairs = (NPERS + 2) / 2;
        int blocks = (npairs + 3) / 4;
        encode_small_p<<<blocks, THR, 0, stream>>>(semb, pers, NPERS, L, xs,
                                                   LQ, enc_pers, pnorms, st);
    }
    persona_hop<<<1, 128, 0, stream>>>(enc_pers, pnorms, RW, st, NPERS);
    big_att_rc<<<1024, THR, 0, stream>>>(semb, keys, values, st, NMEM);
    mid_hop<<<1, 128, 0, stream>>>(RW, R2W, enc_pers, pnorms, st, NPERS);
    big_att_rc<<<1024, THR, 0, stream>>>(semb, keys, values, st, NMEM);
    finish_hop<<<1, 128, 0, stream>>>(R2W, st);
    int nblk5 = (((NCAND + 1) / 2) + 3) / 4;
    k5_final<<<nblk5, THR, 0, stream>>>(cemb, cands, NCAND, st, out);

    (void)n_in; (void)out_size;
}

// Round 8
// 262.018 us; speedup vs baseline: 1.4405x; 1.0270x over previous
//
#include <hip/hip_runtime.h>
#include <math.h>
#include <stdint.h>

#define D 128
#define EPS 1e-6f
typedef unsigned short u16;

#define NBK 32                    // reduction buckets (r21/r22)
#define BSTR 132                  // bucket stride: 128 acc + 1 esum + pad
#define H1OFF 512                 // hop-1 bucket base in st
#define H2OFF (512 + NBK * BSTR)  // hop-2 bucket base

// ---------------------------------------------------------------------------
// st layout (floats): [0..127] q; [128..255] q_plus1; [384] ||q||;
// [385] ||q_plus1||; [H1OFF + b*BSTR + ch] hop-1 bucket b (ch 128 = esum);
// [H2OFF + ...] hop-2 buckets. (256/386 kept for fallback only.)
// Rules: no global atomic scatters (r8); 1-block serial gathers are latency
// traps (r11) — but 1-block *compute* (persona) is ~3us, acceptable;
// grid.sync >> launch gap (r14); gather = max(FETCH/3.4TB/s, issue rate),
// contiguous >=128B unconditional load streams only (r15/r17/r19).
// r21 (round 7, confirmed): same-address atomic tails cost ~30us/kernel at
// 1024 blocks; 16-bucket staging recovered ~60us. Harness poison fill
// (~40us, 268MB) runs INSIDE dur_us each iteration — fixed floor.
// r22 (this round): hop-1 fused into the K+V gather — the fp32 key/value
// row-sums are already in registers, so dot->exp->acc costs zero re-reads;
// attcv2#1 (50MB + launch) deleted. Persona becomes a standalone 1-block
// launch before the gather. NBK 16->32 keeps 64 blocks/bucket at 2048 blocks.
// ---------------------------------------------------------------------------

__device__ __forceinline__ float wave_sum(float v) {
#pragma unroll
    for (int off = 32; off > 0; off >>= 1) v += __shfl_xor(v, off, 64);
    return v;
}
__device__ __forceinline__ float halfwave_sum(float v) {
#pragma unroll
    for (int off = 16; off > 0; off >>= 1) v += __shfl_xor(v, off, 32);
    return v;
}

__device__ __forceinline__ float bf2f(u16 h) {
    union { unsigned u; float f; } x;
    x.u = ((unsigned)h) << 16;
    return x.f;
}
__device__ __forceinline__ float bflo(unsigned u) { return bf2f((u16)(u & 0xffff)); }
__device__ __forceinline__ float bfhi(unsigned u) { return bf2f((u16)(u >> 16)); }
__device__ __forceinline__ u16 f2bf(float f) {  // round-to-nearest-even
    union { float f; unsigned u; } x;
    x.f = f;
    unsigned u = x.u;
    return (u16)((u + 0x7fff + ((u >> 16) & 1)) >> 16);
}
__device__ __forceinline__ unsigned pack2(float a, float b) {
    return (unsigned)f2bf(a) | ((unsigned)f2bf(b) << 16);
}

// ===========================================================================
// prep_k: blocks [0,nbA) convert semb fp32 -> bf16 ROW-MAJOR; last 3 blocks
// do the small encodes (persona rows + q).
// ===========================================================================
__global__ void prep_k(const float* __restrict__ semb, u16* __restrict__ tbl,
                       int V, const int* __restrict__ pers, int NP,
                       const int* __restrict__ xs, int LQ,
                       float* __restrict__ enc_pers, float* __restrict__ pnorms,
                       float* __restrict__ st, int nbA) {
    const int tid = threadIdx.x;
    const int bid = blockIdx.x;
    if (bid < nbA) {
        const int n = V * 64;  // channel-pairs
        const int stride = nbA * 256;
        for (int i = bid * 256 + tid; i < n; i += stride) {
            const int v = i >> 6;
            const int c2 = i & 63;
            const float2 ab = *(const float2*)(semb + (long)v * D + 2 * c2);
            *(unsigned*)(tbl + (long)v * D + 2 * c2) = pack2(ab.x, ab.y);
        }
    } else {
        const int lane = tid & 63;
        const int half = lane >> 5;
        const int hl = lane & 31;
        const int w0 = (bid - nbA) * 4 + (tid >> 6);
        const int npr = NP + 1;  // +1 virtual q row
        const int npairs = (npr + 1) >> 1;
        for (int w = w0; w < npairs; w += 12) {
            const int row = 2 * w + half;
            const bool valid = row < npr;
            const int rowc = valid ? row : NP;
            const bool isq = (rowc == NP);
            const int* ids = isq ? xs : (pers + (long)rowc * 20);
            const int L = isq ? LQ : 20;
            int myid = 0;
            if (hl < L) myid = ids[hl];
            float4 acc = {0.f, 0.f, 0.f, 0.f};
            for (int t = 0; t < L; ++t) {
                const int idx = __shfl(myid, (half << 5) + t, 64);
                const float4 e = *(const float4*)(semb + (long)idx * D + 4 * hl);
                acc.x += e.x; acc.y += e.y; acc.z += e.z; acc.w += e.w;
            }
            if (valid) {
                float* outp = isq ? st : (enc_pers + (long)rowc * D);
                *(float4*)(outp + 4 * hl) = acc;
                float sq = acc.x * acc.x + acc.y * acc.y + acc.z * acc.z + acc.w * acc.w;
                sq = halfwave_sum(sq);
                if (hl == 0) {
                    if (isq) st[384] = sqrtf(sq);
                    else pnorms[rowc] = sqrtf(sq);
                }
            }
        }
    }
}

// ===========================================================================
// persona hop device fn. zb=1: zero both hop bucket banks (stored path).
// zb=0 (fallback): zero old 256/386 fields.
// ===========================================================================
__device__ void persona_dev(const float* __restrict__ pers_rows,
                            const float* __restrict__ pnorms,
                            const float* __restrict__ W, float* __restrict__ st,
                            int NP, float* smem, int tid, int zb) {
    float* qsh = smem;          // 128
    float* qh = smem + 128;     // 128
    float* att = smem + 256;    // 64
    float* red = smem + 320;    // 2
    if (tid < D) qsh[tid] = st[tid];
    __syncthreads();
    if (tid < NP) {
        float dot = 0.f;
        const float* pr = pers_rows + (long)tid * D;
        for (int d2 = 0; d2 < D; ++d2) dot += pr[d2] * qsh[d2];
        att[tid] = dot / fmaxf(pnorms[tid] * st[384], EPS);
    }
    __syncthreads();
    if (tid == 0) {
        float m = -1e30f;
        for (int p = 0; p < NP; ++p) m = fmaxf(m, att[p]);
        float s = 0.f;
        for (int p = 0; p < NP; ++p) { att[p] = __expf(att[p] - m); s += att[p]; }
        float inv = 1.f / s;
        for (int p = 0; p < NP; ++p) att[p] *= inv;
    }
    __syncthreads();
    if (tid < D) {
        float h = 0.f;
        for (int p = 0; p < NP; ++p) h += att[p] * pers_rows[(long)p * D + tid];
        qh[tid] = qsh[tid] + h;
    }
    __syncthreads();
    float qp = 0.f;
    if (tid < D) {
        for (int d2 = 0; d2 < D; ++d2) qp += W[(long)tid * D + d2] * qh[d2];
        st[128 + tid] = qp;
    }
    float sq = wave_sum(qp * qp);
    if ((tid & 63) == 0 && tid < 128) red[tid >> 6] = sq;
    __syncthreads();
    if (tid == 0) st[385] = sqrtf(red[0] + red[1]);
    if (zb) {
        for (int i = tid; i < 2 * NBK * BSTR; i += (int)blockDim.x)
            st[H1OFF + i] = 0.f;
    } else {
        if (tid < D) st[256 + tid] = 0.f;
        if (tid == 0) st[386] = 0.f;
    }
}

__global__ void persona_hop_s(const float* __restrict__ pers_rows,
                              const float* __restrict__ pnorms,
                              const float* __restrict__ W,
                              float* __restrict__ st, int NP) {
    __shared__ float smem[336];
    persona_dev(pers_rows, pnorms, W, st, NP, smem, (int)threadIdx.x, 1);
}

// ===========================================================================
// mid_dev_s: full mid-hop per block into SMEM only. acc1/esum1 from hop-1
// buckets. Writes qp_out[128], *qpn_out. Deterministic per block.
// ===========================================================================
__device__ void mid_dev_s(const float* __restrict__ W1, const float* __restrict__ W2,
                          const float* __restrict__ pers_rows,
                          const float* __restrict__ pnorms,
                          const float* __restrict__ st,
                          float* __restrict__ qp_out, float* __restrict__ qpn_out,
                          float* smem, int tid, int NP) {
    float* qh = smem;           // 128
    float* qsh = smem + 128;    // 128
    float* att = smem + 256;    // 64
    float* red = smem + 320;    // 2
    float esum = 0.f;
#pragma unroll
    for (int b = 0; b < NBK; ++b) esum += st[H1OFF + b * BSTR + 128];
    const float inv = 1.f / esum;
    if (tid < D) {
        float a = 0.f;
#pragma unroll
        for (int b = 0; b < NBK; ++b) a += st[H1OFF + b * BSTR + tid];
        qh[tid] = st[128 + tid] + a * inv;
    }
    __syncthreads();
    float qn = 0.f;
    if (tid < D) {
        for (int d2 = 0; d2 < D; ++d2) qn += W1[(long)tid * D + d2] * qh[d2];
        qsh[tid] = qn;
    }
    float sq = wave_sum(qn * qn);
    if ((tid & 63) == 0 && tid < 128) red[tid >> 6] = sq;
    __syncthreads();
    const float qnorm = sqrtf(red[0] + red[1]);
    if (tid < NP) {
        float dot = 0.f;
        for (int d2 = 0; d2 < D; ++d2) dot += pers_rows[(long)tid * D + d2] * qsh[d2];
        att[tid] = dot / fmaxf(pnorms[tid] * qnorm, EPS);
    }
    __syncthreads();
    if (tid == 0) {
        float m = -1e30f;
        for (int p = 0; p < NP; ++p) m = fmaxf(m, att[p]);
        float s = 0.f;
        for (int p = 0; p < NP; ++p) { att[p] = __expf(att[p] - m); s += att[p]; }
        float is = 1.f / s;
        for (int p = 0; p < NP; ++p) att[p] *= is;
    }
    __syncthreads();
    if (tid < D) {
        float h = 0.f;
        for (int p = 0; p < NP; ++p) h += att[p] * pers_rows[(long)p * D + tid];
        qh[tid] = qsh[tid] + h;
    }
    __syncthreads();
    float qp = 0.f;
    if (tid < D) {
        for (int d2 = 0; d2 < D; ++d2) qp += W2[(long)tid * D + d2] * qh[d2];
        qp_out[tid] = qp;
    }
    float sq2 = wave_sum(qp * qp);
    if ((tid & 63) == 0 && tid < 128) red[tid >> 6] = sq2;
    __syncthreads();
    if (tid == 0) *qpn_out = sqrtf(red[0] + red[1]);
    __syncthreads();
}

// ===========================================================================
// kvh1_k: fused K+V gather + hop-1 (r22). Half-wave per row; 40 unconditional
// ushort4 row-loads (256B contiguous, r19). Key/value fp32 row-sums stay in
// registers: kb/vb/knorms stored for hop-2, and hop-1's dot->exp->acc uses
// the register copies directly (zero re-read). Bucketed tail (r21).
// Requires persona_hop_s completed (qp in st[128..255], st[385]).
// ===========================================================================
__global__ void kvh1_k(const u16* __restrict__ tbl, const int* __restrict__ kids,
                       const int* __restrict__ vids, int N,
                       float* __restrict__ kb, u16* __restrict__ vb,
                       float* __restrict__ knorms, float* __restrict__ st) {
    __shared__ float qp_s[128];
    __shared__ float qpn_s;
    __shared__ float rsm[129];
    const int tid = threadIdx.x;
    if (tid < 128) qp_s[tid] = st[128 + tid];
    if (tid == 128) qpn_s = st[385];
    __syncthreads();
    const int lane = tid & 63;
    const int half = lane >> 5;
    const int hl = lane & 31;
    const float4 qp4 = *(const float4*)(qp_s + 4 * hl);
    const float qpn = qpn_s;
    const int ghw = (int)((blockIdx.x * blockDim.x + tid) >> 5);
    const int nhw = (int)((gridDim.x * blockDim.x) >> 5);
    float a0 = 0.f, a1 = 0.f, a2 = 0.f, a3 = 0.f;
    float esum = 0.f;
    for (int i = ghw; i < N; i += nhw) {
        int kid = 0, vid = 0;
        if (hl < 20) {
            kid = kids[(long)i * 20 + hl];
            vid = vids[(long)i * 20 + hl];
        }
        float k0 = 0.f, k1 = 0.f, k2 = 0.f, k3 = 0.f;
        float v0 = 0.f, v1 = 0.f, v2 = 0.f, v3 = 0.f;
#pragma unroll
        for (int t = 0; t < 20; ++t) {
            const int kj = __shfl(kid, (half << 5) + t, 64);
            const int vj = __shfl(vid, (half << 5) + t, 64);
            const ushort4 ke = *(const ushort4*)(tbl + (long)kj * D + 4 * hl);
            const ushort4 ve = *(const ushort4*)(tbl + (long)vj * D + 4 * hl);
            k0 += bf2f(ke.x); k1 += bf2f(ke.y); k2 += bf2f(ke.z); k3 += bf2f(ke.w);
            v0 += bf2f(ve.x); v1 += bf2f(ve.y); v2 += bf2f(ve.z); v3 += bf2f(ve.w);
        }
        float4 kr;
        kr.x = k0; kr.y = k1; kr.z = k2; kr.w = k3;
        *(float4*)(kb + (long)i * D + 4 * hl) = kr;
        uint2 pv;
        pv.x = pack2(v0, v1);
        pv.y = pack2(v2, v3);
        *(uint2*)(vb + (long)i * D + 4 * hl) = pv;
        const float nsq = halfwave_sum(k0 * k0 + k1 * k1 + k2 * k2 + k3 * k3);
        const float knorm = sqrtf(nsq);
        if (hl == 0) knorms[i] = knorm;
        // ---- hop 1 in-register (fp32 k and v row-sums)
        const float part = k0 * qp4.x + k1 * qp4.y + k2 * qp4.z + k3 * qp4.w;
        const float dot = halfwave_sum(part);
        const float c = dot / fmaxf(knorm * qpn, EPS);
        const float e = __expf(c);
        a0 += e * v0; a1 += e * v1; a2 += e * v2; a3 += e * v3;
        if (hl == 0) esum += e;
    }
    a0 += __shfl_xor(a0, 32, 64);
    a1 += __shfl_xor(a1, 32, 64);
    a2 += __shfl_xor(a2, 32, 64);
    a3 += __shfl_xor(a3, 32, 64);
    esum += __shfl_xor(esum, 32, 64);
    if (tid < 129) rsm[tid] = 0.f;
    __syncthreads();
    if (half == 0) {
        atomicAdd(&rsm[4 * hl + 0], a0);
        atomicAdd(&rsm[4 * hl + 1], a1);
        atomicAdd(&rsm[4 * hl + 2], a2);
        atomicAdd(&rsm[4 * hl + 3], a3);
        if (hl == 0) atomicAdd(&rsm[128], esum);
    }
    __syncthreads();
    const int aoff = H1OFF + (int)(blockIdx.x & (NBK - 1)) * BSTR;
    if (tid < 128) atomicAdd(&st[aoff + tid], rsm[tid]);
    if (tid == 128) atomicAdd(&st[aoff + 128], rsm[128]);
}

// ===========================================================================
// attcv2_k (hop 2): per-block mid prologue, then streaming kb.qp2 -> e ->
// acc e*vb. Bucketed tail. GRID <= 1024.
// ===========================================================================
__global__ void attcv2_k(const float* __restrict__ kb, const u16* __restrict__ vb,
                         const float* __restrict__ knorms,
                         const float* __restrict__ W1, const float* __restrict__ W2,
                         const float* __restrict__ enc_pers,
                         const float* __restrict__ pnorms,
                         float* __restrict__ st, int N, int NP) {
    __shared__ float msm[324];
    __shared__ float qp_s[128];
    __shared__ float qpn_s;
    __shared__ float rsm[129];
    const int tid = threadIdx.x;
    mid_dev_s(W1, W2, enc_pers, pnorms, st, qp_s, &qpn_s, msm, tid, NP);
    __syncthreads();
    const int lane = tid & 63;
    const int half = lane >> 5;
    const int hl = lane & 31;
    const float4 qp4 = *(const float4*)(qp_s + 4 * hl);
    const float qpn = qpn_s;
    const int ghw = (int)((blockIdx.x * blockDim.x + tid) >> 5);
    const int nhw = (int)((gridDim.x * blockDim.x) >> 5);
    float a0 = 0.f, a1 = 0.f, a2 = 0.f, a3 = 0.f;
    float esum = 0.f;
    for (int i = ghw; i < N; i += nhw) {
        const float4 kr = *(const float4*)(kb + (long)i * D + 4 * hl);
        const float part = kr.x * qp4.x + kr.y * qp4.y + kr.z * qp4.z + kr.w * qp4.w;
        const float dot = halfwave_sum(part);
        const float c = dot / fmaxf(knorms[i] * qpn, EPS);
        const float e = __expf(c);
        const uint2 vh = *(const uint2*)(vb + (long)i * D + 4 * hl);
        a0 += e * bflo(vh.x);
        a1 += e * bfhi(vh.x);
        a2 += e * bflo(vh.y);
        a3 += e * bfhi(vh.y);
        if (hl == 0) esum += e;
    }
    a0 += __shfl_xor(a0, 32, 64);
    a1 += __shfl_xor(a1, 32, 64);
    a2 += __shfl_xor(a2, 32, 64);
    a3 += __shfl_xor(a3, 32, 64);
    esum += __shfl_xor(esum, 32, 64);
    if (tid < 129) rsm[tid] = 0.f;
    __syncthreads();
    if (half == 0) {
        atomicAdd(&rsm[4 * hl + 0], a0);
        atomicAdd(&rsm[4 * hl + 1], a1);
        atomicAdd(&rsm[4 * hl + 2], a2);
        atomicAdd(&rsm[4 * hl + 3], a3);
        if (hl == 0) atomicAdd(&rsm[128], esum);
    }
    __syncthreads();
    const int aoff = H2OFF + (int)(blockIdx.x & (NBK - 1)) * BSTR;
    if (tid < 128) atomicAdd(&st[aoff + tid], rsm[tid]);
    if (tid == 128) atomicAdd(&st[aoff + 128], rsm[128]);
}

// ===========================================================================
// k5f: per-block mid + finish prologue (reads hop-2 buckets), then fp32
// candidate gather + cosine.
// ===========================================================================
__global__ void k5f(const float* __restrict__ W1, const float* __restrict__ W2,
                    const float* __restrict__ enc_pers,
                    const float* __restrict__ pnorms,
                    const float* __restrict__ cemb,
                    const int* __restrict__ cands, int NC, int NP,
                    const float* __restrict__ st, float* __restrict__ out) {
    __shared__ float msm[324];
    __shared__ float qp2_s[128];
    __shared__ float qpn2_s;
    __shared__ float qhf[128];
    __shared__ float qv[D];
    __shared__ float red2[2];
    __shared__ float qns;
    const int tid = threadIdx.x;
    mid_dev_s(W1, W2, enc_pers, pnorms, st, qp2_s, &qpn2_s, msm, tid, NP);
    float esum2 = 0.f;
#pragma unroll
    for (int b = 0; b < NBK; ++b) esum2 += st[H2OFF + b * BSTR + 128];
    const float inv2 = 1.f / esum2;
    if (tid < D) {
        float a = 0.f;
#pragma unroll
        for (int b = 0; b < NBK; ++b) a += st[H2OFF + b * BSTR + tid];
        qhf[tid] = qp2_s[tid] + a * inv2;
    }
    __syncthreads();
    float qn = 0.f;
    if (tid < D) {
        for (int d2 = 0; d2 < D; ++d2) qn += W2[(long)tid * D + d2] * qhf[d2];
        qv[tid] = qn;
    }
    float sq = wave_sum(qn * qn);
    if ((tid & 63) == 0 && tid < 128) red2[tid >> 6] = sq;
    __syncthreads();
    if (tid == 0) qns = sqrtf(red2[0] + red2[1]);
    __syncthreads();
    // ---- candidate gather + cosine
    const int lane = tid & 63;
    const int half = lane >> 5;
    const int hl = lane & 31;
    const int gw = (int)((blockIdx.x * blockDim.x + tid) >> 6);
    const int nw = (int)((gridDim.x * blockDim.x) >> 6);
    const float4 q4 = *(const float4*)(qv + 4 * hl);
    const float qnf = qns;
    const int npair = (NC + 1) >> 1;
    for (int p = gw; p < npair; p += nw) {
        const int row = 2 * p + half;
        const bool valid = row < NC;
        const int rowc = valid ? row : (NC - 1);
        int myid = 0;
        if (hl < 20) myid = cands[(long)rowc * 20 + hl];
        float4 acc = {0.f, 0.f, 0.f, 0.f};
#pragma unroll
        for (int t = 0; t < 20; ++t) {
            const int idx = __shfl(myid, (half << 5) + t, 64);
            const float4 e = *(const float4*)(cemb + (long)idx * D + 4 * hl);
            acc.x += e.x; acc.y += e.y; acc.z += e.z; acc.w += e.w;
        }
        float dot = halfwave_sum(acc.x * q4.x + acc.y * q4.y +
                                 acc.z * q4.z + acc.w * q4.w);
        float nsq = halfwave_sum(acc.x * acc.x + acc.y * acc.y +
                                 acc.z * acc.z + acc.w * acc.w);
        if (valid && hl == 0) out[row] = dot / fmaxf(sqrtf(nsq) * qnf, EPS);
    }
}

// ===========================================================================
// Fallback path kernels (no/undersized workspace): fp32 on-the-fly.
// ===========================================================================
__global__ void encode_small_p(const float* __restrict__ emb,
                               const int* __restrict__ pers, int NP, int LP,
                               const int* __restrict__ xs, int LQ,
                               float* __restrict__ pers_rows,
                               float* __restrict__ pnorms,
                               float* __restrict__ st) {
    const int lane = threadIdx.x & 63;
    const int half = lane >> 5;
    const int hl = lane & 31;
    int gw = (int)((blockIdx.x * blockDim.x + threadIdx.x) >> 6);
    int nw = (int)((gridDim.x * blockDim.x) >> 6);
    const int npr = NP + 1;
    const int npairs = (npr + 1) >> 1;
    for (int p = gw; p < npairs; p += nw) {
        const int row = 2 * p + half;
        const bool valid = row < npr;
        const int rowc = valid ? row : NP;
        const bool isq = (rowc == NP);
        const int* ids = isq ? xs : (pers + (long)rowc * LP);
        const int L = isq ? LQ : LP;
        int myid = 0;
        if (hl < L) myid = ids[hl];
        float4 acc = {0.f, 0.f, 0.f, 0.f};
        for (int t = 0; t < L; ++t) {
            const int idx = __shfl(myid, (half << 5) + t, 64);
            const float4 e = *(const float4*)(emb + (long)idx * D + 4 * hl);
            acc.x += e.x; acc.y += e.y; acc.z += e.z; acc.w += e.w;
        }
        if (valid) {
            float* outp = isq ? st : (pers_rows + (long)rowc * D);
            *(float4*)(outp + 4 * hl) = acc;
            float sq = acc.x * acc.x + acc.y * acc.y + acc.z * acc.z + acc.w * acc.w;
            sq = halfwave_sum(sq);
            if (hl == 0) {
                if (isq) st[384] = sqrtf(sq);
                else pnorms[rowc] = sqrtf(sq);
            }
        }
    }
}

__global__ void persona_hop(const float* __restrict__ pers_rows,
                            const float* __restrict__ pnorms,
                            const float* __restrict__ W,
                            float* __restrict__ st, int NP) {
    __shared__ float smem[336];
    persona_dev(pers_rows, pnorms, W, st, NP, smem, (int)threadIdx.x, 0);
}

__global__ void mid_hop(const float* __restrict__ W1, const float* __restrict__ W2,
                        const float* __restrict__ pers_rows,
                        const float* __restrict__ pnorms,
                        float* __restrict__ st, int NP) {
    __shared__ float qh[D];
    __shared__ float qsh[D];
    __shared__ float att[64];
    __shared__ float red[2];
    int tid = threadIdx.x;
    float inv = 1.f / st[386];
    qh[tid] = st[128 + tid] + st[256 + tid] * inv;
    __syncthreads();
    float qn = 0.f;
    for (int d2 = 0; d2 < D; ++d2) qn += W1[tid * D + d2] * qh[d2];
    qsh[tid] = qn;
    st[tid] = qn;
    float sq = wave_sum(qn * qn);
    if ((tid & 63) == 0) red[tid >> 6] = sq;
    __syncthreads();
    float qnorm = sqrtf(red[0] + red[1]);
    if (tid == 0) st[384] = qnorm;
    if (tid < NP) {
        float dot = 0.f;
        for (int d2 = 0; d2 < D; ++d2) dot += pers_rows[tid * D + d2] * qsh[d2];
        att[tid] = dot / fmaxf(pnorms[tid] * qnorm, EPS);
    }
    __syncthreads();
    if (tid == 0) {
        float m = -1e30f;
        for (int p = 0; p < NP; ++p) m = fmaxf(m, att[p]);
        float s = 0.f;
        for (int p = 0; p < NP; ++p) { att[p] = __expf(att[p] - m); s += att[p]; }
        float is = 1.f / s;
        for (int p = 0; p < NP; ++p) att[p] *= is;
    }
    __syncthreads();
    float h = 0.f;
    for (int p = 0; p < NP; ++p) h += att[p] * pers_rows[p * D + tid];
    qh[tid] = qsh[tid] + h;
    __syncthreads();
    float qp = 0.f;
    for (int d2 = 0; d2 < D; ++d2) qp += W2[tid * D + d2] * qh[d2];
    st[128 + tid] = qp;
    float sq2 = wave_sum(qp * qp);
    if ((tid & 63) == 0) red[tid >> 6] = sq2;
    __syncthreads();
    if (tid == 0) st[385] = sqrtf(red[0] + red[1]);
    st[256 + tid] = 0.f;
    if (tid == 0) st[386] = 0.f;
}

__global__ void finish_hop(const float* __restrict__ W, float* __restrict__ st) {
    __shared__ float qh[D];
    __shared__ float red[2];
    int tid = threadIdx.x;
    float inv = 1.f / st[386];
    qh[tid] = st[128 + tid] + st[256 + tid] * inv;
    __syncthreads();
    float qn = 0.f;
    for (int d2 = 0; d2 < D; ++d2) qn += W[tid * D + d2] * qh[d2];
    st[tid] = qn;
    float sq = wave_sum(qn * qn);
    if ((tid & 63) == 0) red[tid >> 6] = sq;
    __syncthreads();
    if (tid == 0) st[384] = sqrtf(red[0] + red[1]);
}

__global__ void k5_final(const float* __restrict__ cemb,
                         const int* __restrict__ cands, int NC,
                         const float* __restrict__ st, float* __restrict__ out) {
    const int lane = threadIdx.x & 63;
    const int half = lane >> 5;
    const int hl = lane & 31;
    const int gw = (int)((blockIdx.x * blockDim.x + threadIdx.x) >> 6);
    const int nw = (int)((gridDim.x * blockDim.x) >> 6);
    const float4 q4 = *(const float4*)(st + 4 * hl);
    const float qn = st[384];
    const int npair = (NC + 1) >> 1;
    for (int p = gw; p < npair; p += nw) {
        const int row = 2 * p + half;
        const bool valid = row < NC;
        const int rowc = valid ? row : (NC - 1);
        int myid = 0;
        if (hl < 20) myid = cands[(long)rowc * 20 + hl];
        float4 acc = {0.f, 0.f, 0.f, 0.f};
#pragma unroll
        for (int t = 0; t < 20; ++t) {
            const int idx = __shfl(myid, (half << 5) + t, 64);
            const float4 e = *(const float4*)(cemb + (long)idx * D + 4 * hl);
            acc.x += e.x; acc.y += e.y; acc.z += e.z; acc.w += e.w;
        }
        float dot = halfwave_sum(acc.x * q4.x + acc.y * q4.y +
                                 acc.z * q4.z + acc.w * q4.w);
        float nsq = halfwave_sum(acc.x * acc.x + acc.y * acc.y +
                                 acc.z * acc.z + acc.w * acc.w);
        if (valid && hl == 0) out[row] = dot / fmaxf(sqrtf(nsq) * qn, EPS);
    }
}

__global__ void big_att_rc(const float* __restrict__ emb,
                           const int* __restrict__ kids,
                           const int* __restrict__ vids,
                           float* __restrict__ st, int N) {
    __shared__ float s[129];
    const int tid = threadIdx.x;
    const int lane = tid & 63;
    const int half = lane >> 5;
    const int hl = lane & 31;
    const int gw = (int)((blockIdx.x * blockDim.x + tid) >> 6);
    const int nw = (int)((gridDim.x * blockDim.x) >> 6);
    const float4 qp = *(const float4*)(st + 128 + 4 * hl);
    const float qpn = st[385];
    float4 hacc = {0.f, 0.f, 0.f, 0.f};
    float esum = 0.f;
    const int npair = (N + 1) >> 1;
    for (int p = gw; p < npair; p += nw) {
        const int row = 2 * p + half;
        const bool valid = row < N;
        const int rowc = valid ? row : (N - 1);
        int kid = 0, vid = 0;
        if (hl < 20) {
            kid = kids[(long)rowc * 20 + hl];
            vid = vids[(long)rowc * 20 + hl];
        }
        float4 ka = {0.f, 0.f, 0.f, 0.f}, va = {0.f, 0.f, 0.f, 0.f};
#pragma unroll
        for (int t = 0; t < 20; ++t) {
            const int ki = __shfl(kid, (half << 5) + t, 64);
            const int vi = __shfl(vid, (half << 5) + t, 64);
            const float4 ke = *(const float4*)(emb + (long)ki * D + 4 * hl);
            const float4 ve = *(const float4*)(emb + (long)vi * D + 4 * hl);
            ka.x += ke.x; ka.y += ke.y; ka.z += ke.z; ka.w += ke.w;
            va.x += ve.x; va.y += ve.y; va.z += ve.z; va.w += ve.w;
        }
        float nsq = halfwave_sum(ka.x * ka.x + ka.y * ka.y + ka.z * ka.z + ka.w * ka.w);
        float dot = halfwave_sum(ka.x * qp.x + ka.y * qp.y + ka.z * qp.z + ka.w * qp.w);
        const float c = dot / fmaxf(sqrtf(nsq) * qpn, EPS);
        float e = __expf(c);
        if (!valid) e = 0.f;
        hacc.x += e * va.x; hacc.y += e * va.y;
        hacc.z += e * va.z; hacc.w += e * va.w;
        if (hl == 0) esum += e;
    }
    hacc.x += __shfl_xor(hacc.x, 32, 64);
    hacc.y += __shfl_xor(hacc.y, 32, 64);
    hacc.z += __shfl_xor(hacc.z, 32, 64);
    hacc.w += __shfl_xor(hacc.w, 32, 64);
    esum += __shfl_xor(esum, 32, 64);
    if (tid < 129) s[tid] = 0.f;
    __syncthreads();
    if (half == 0) {
        atomicAdd(&s[4 * hl + 0], hacc.x);
        atomicAdd(&s[4 * hl + 1], hacc.y);
        atomicAdd(&s[4 * hl + 2], hacc.z);
        atomicAdd(&s[4 * hl + 3], hacc.w);
        if (hl == 0) atomicAdd(&s[128], esum);
    }
    __syncthreads();
    if (tid < 128) atomicAdd(&st[256 + tid], s[tid]);
    if (tid == 128) atomicAdd(&st[386], s[128]);
}

static inline size_t align16(size_t b) { return (b + 15) & ~(size_t)15; }

extern "C" void kernel_launch(void* const* d_in, const int* in_sizes, int n_in,
                              void* d_out, int out_size, void* d_ws, size_t ws_size,
                              hipStream_t stream) {
    const int* xs = (const int*)d_in[0];
    const int* cands = (const int*)d_in[1];
    const int* pers = (const int*)d_in[2];
    const int* keys = (const int*)d_in[3];
    const int* values = (const int*)d_in[4];
    const float* semb = (const float*)d_in[6];
    const float* cemb = (const float*)d_in[7];
    const float* RW = (const float*)d_in[8];
    const float* R2W = (const float*)d_in[9];
    float* out = (float*)d_out;

    const int L = 20;
    const int LQ = in_sizes[0];
    const int VD = in_sizes[6];         // V*D (elements)
    const int V = VD / D;               // 50000
    const int NMEM = in_sizes[3] / L;   // 65536
    const int NCAND = in_sizes[1] / L;  // 10000
    const int NPERS = in_sizes[2] / L;  // 20

    size_t need = align16((size_t)VD * 2) + align16((size_t)NMEM * D * 2) +
                  align16((size_t)NMEM * D * 4) + align16((size_t)NMEM * 4) +
                  align16((size_t)NPERS * D * 4) + align16((size_t)NPERS * 4) +
                  16384 * 4;
    bool stored = (d_ws != nullptr) && (ws_size >= need) && (NMEM % 4 == 0) &&
                  (NMEM <= 65536) && ((VD & 3) == 0) && (LQ <= 32) &&
                  (NPERS <= 64);

    const int THR = 256;
    char* base = (char*)d_ws;
    u16 *tbl16 = nullptr, *vb = nullptr;
    float *kb = nullptr, *knorms = nullptr;
    if (stored) {
        tbl16 = (u16*)base;  base += align16((size_t)VD * 2);         // row-major
        vb = (u16*)base;     base += align16((size_t)NMEM * D * 2);   // row-major
        kb = (float*)base;   base += align16((size_t)NMEM * D * 4);   // fp32 key sums
        knorms = (float*)base; base += align16((size_t)NMEM * 4);
    }
    float* enc_pers = (float*)base; base += align16((size_t)NPERS * D * 4);
    float* pnorms = (float*)base;   base += align16((size_t)NPERS * 4);
    float* st = (float*)base;

    if (stored) {
        const int nbA = 2048;
        // 1. prep: semb -> bf16 row-major || small encodes
        prep_k<<<nbA + 3, THR, 0, stream>>>(semb, tbl16, V, pers, NPERS, xs, LQ,
                                            enc_pers, pnorms, st, nbA);
        // 2. persona hop (1 block; tiny compute, sets qp + zeroes buckets)
        persona_hop_s<<<1, 128, 0, stream>>>(enc_pers, pnorms, RW, st, NPERS);
        // 3. fused K+V gather + hop-1 (in-register, bucketed tail — r22)
        kvh1_k<<<2048, THR, 0, stream>>>(tbl16, keys, values, NMEM, kb, vb,
                                         knorms, st);
        // 4. hop 2: per-block mid prologue + streaming kb/vb pass
        attcv2_k<<<1024, THR, 0, stream>>>(kb, vb, knorms, RW, R2W, enc_pers,
                                           pnorms, st, NMEM, NPERS);
        // 5. per-block mid+finish prologue + fp32 candidate gather
        k5f<<<640, THR, 0, stream>>>(RW, R2W, enc_pers, pnorms, cemb, cands,
                                     NCAND, NPERS, st, out);
        (void)n_in; (void)out_size;
        return;
    }

    // -------- fallback: fp32 on-the-fly gather --------
    {
        int npairs = (NPERS + 2) / 2;
        int blocks = (npairs + 3) / 4;
        encode_small_p<<<blocks, THR, 0, stream>>>(semb, pers, NPERS, L, xs,
                                                   LQ, enc_pers, pnorms, st);
    }
    persona_hop<<<1, 128, 0, stream>>>(enc_pers, pnorms, RW, st, NPERS);
    big_att_rc<<<1024, THR, 0, stream>>>(semb, keys, values, st, NMEM);
    mid_hop<<<1, 128, 0, stream>>>(RW, R2W, enc_pers, pnorms, st, NPERS);
    big_att_rc<<<1024, THR, 0, stream>>>(semb, keys, values, st, NMEM);
    finish_hop<<<1, 128, 0, stream>>>(R2W, st);
    int nblk5 = (((NCAND + 1) / 2) + 3) / 4;
    k5_final<<<nblk5, THR, 0, stream>>>(cemb, cands, NCAND, st, out);

    (void)n_in; (void)out_size;
}